// Round 1
// baseline (3483.860 us; speedup 1.0000x reference)
//
#include <hip/hip_runtime.h>
#include <hip/hip_bf16.h>

#define NN 10000
#define NE 50000

__device__ __forceinline__ float silu_f(float v){ return v / (1.0f + __expf(-v)); }

// ---------------- K0: h = rmsnorm(x, gamma1) -> bf16 ----------------
__global__ __launch_bounds__(256) void k_rms1(const float* __restrict__ x,
                                              const float* __restrict__ gamma,
                                              __hip_bfloat16* __restrict__ h){
  int idx = blockIdx.x*256 + threadIdx.x;
  if (idx >= NN*64) return;
  int n = idx>>6, c = idx&63;
  const float* xp = x + (size_t)n*1600 + c;
  float ss = 0.f;
#pragma unroll
  for (int i=0;i<25;i++){ float v = xp[i*64]; ss += v*v; }
  float inv = gamma[c] * rsqrtf(ss*(1.f/25.f) + 1e-6f);
  __hip_bfloat16* hp = h + (size_t)n*1600 + c;
#pragma unroll
  for (int i=0;i<25;i++) hp[i*64] = __float2bfloat16(xp[i*64]*inv);
}

// ---------------- K1: radial MLP + alpha/gate per edge ----------------
// 16 edges per block, one edge per wave x 4 sequential sub-iterations.
// LDS slot per wave (floats): EF@0(96) R1@96(64) R2@160(64) RF@224(640)
//                             XR@864(128) W0@992(25) T@1024(128)  -> 1152
__global__ __launch_bounds__(256) void k_alpha(
  const __hip_bfloat16* __restrict__ h, const int* __restrict__ ei,
  const int* __restrict__ an, const float* __restrict__ edist,
  const float* __restrict__ wig, const float* __restrict__ stab,
  const float* __restrict__ ttab,
  const float* __restrict__ rw1, const float* __restrict__ rb1,
  const float* __restrict__ rw2, const float* __restrict__ rb2,
  const float* __restrict__ rw3, const float* __restrict__ rb3,
  const float* __restrict__ w0e, const float* __restrict__ adot,
  float* __restrict__ expa, float* __restrict__ asum,
  __hip_bfloat16* __restrict__ rfS, __hip_bfloat16* __restrict__ gateS)
{
  __shared__ float S4[4][1152];
  const int wv = threadIdx.x>>6, lane = threadIdx.x&63;
  float* S = S4[wv];
  for (int sub=0; sub<4; ++sub){
    const int e = blockIdx.x*16 + sub*4 + wv;
    const int src = ei[e], dst = ei[NE+e];
    if (lane<32){
      S[lane]    = edist[(size_t)e*32 + lane];
      S[64+lane] = ttab[(size_t)an[dst]*32 + lane];
    } else {
      S[lane]    = stab[(size_t)an[src]*32 + (lane-32)];
    }
    if (lane<25) S[992+lane] = wig[(size_t)e*625 + lane];
    __syncthreads();
    { // r1 = silu(ef @ rad_w1 + b1)
      float a = rb1[lane];
#pragma unroll 8
      for (int k=0;k<96;k++) a += S[k]*rw1[k*64+lane];
      S[96+lane] = silu_f(a);
    }
    __syncthreads();
    { // r2
      float a = rb2[lane];
#pragma unroll 8
      for (int k=0;k<64;k++) a += S[96+k]*rw2[k*64+lane];
      S[160+lane] = silu_f(a);
    }
    __syncthreads();
    { // r3: 640 outputs, 10 per lane; keep f32 in LDS, store bf16
      float acc[10];
#pragma unroll
      for (int m=0;m<10;m++) acc[m] = rb3[lane + 64*m];
      for (int k=0;k<64;k++){
        float rv = S[160+k];
        const float* wp = rw3 + (size_t)k*640 + lane;
#pragma unroll
        for (int m=0;m<10;m++) acc[m] += rv*wp[64*m];
      }
#pragma unroll
      for (int m=0;m<10;m++){
        S[224 + lane + 64*m] = acc[m];
        rfS[(size_t)e*640 + lane + 64*m] = __float2bfloat16(acc[m]);
      }
    }
    { // xe0 = wigner_row0 . [h_src | h_dst], then * r0
      const __hip_bfloat16* hs = h + (size_t)src*1600;
      const __hip_bfloat16* hd = h + (size_t)dst*1600;
      float xs=0.f, xd=0.f;
#pragma unroll
      for (int j=0;j<25;j++){
        float w0 = S[992+j];
        xs += w0*__bfloat162float(hs[j*64+lane]);
        xd += w0*__bfloat162float(hd[j*64+lane]);
      }
      S[864+lane]    = xs*S[224+lane];      // same-lane RF entries (m=0,1)
      S[864+64+lane] = xd*S[224+64+lane];
    }
    __syncthreads();
    { // extra = xe0r @ W0_extra : alpha_f cols [0,128), gate cols [128,192)
      float f0=0.f, f1=0.f, g=0.f;
#pragma unroll 8
      for (int c=0;c<128;c++){
        float xv = S[864+c];
        const float* wp = w0e + (size_t)c*192;
        f0 += xv*wp[lane];
        f1 += xv*wp[64+lane];
        g  += xv*wp[128+lane];
      }
      S[1024+lane]    = silu_f(f0)*adot[lane];
      S[1024+64+lane] = silu_f(f1)*adot[64+lane];
      gateS[(size_t)e*64+lane] = __float2bfloat16(g);
    }
    __syncthreads();
    if (lane<8){
      float s=0.f;
#pragma unroll
      for (int a=0;a<16;a++) s += S[1024+lane*16+a];
      float ea = __expf(s);       // no max-shift: alpha is O(0.1), safe
      expa[(size_t)e*8+lane] = ea;
      unsafeAtomicAdd(&asum[(size_t)dst*8+lane], ea);
    }
    __syncthreads();
  }
}

// ---------------- K3: main fused edge kernel ----------------
// LDS pool (floats): w@0(700, stride 28) rfull@700(640) gateL@1340(64)
// ahead@1404(8)+pad  xe@1416(3200) hcat@4616(3200, aliased as pbuf)
// msgs@7816(1600) sg@9416(2304)  -> total 11720 (46.9 KB)
__global__ __launch_bounds__(256) void k_edge(
  const __hip_bfloat16* __restrict__ h, const int* __restrict__ ei,
  const float* __restrict__ wig, const float* __restrict__ W1,
  const float* __restrict__ tog, const float* __restrict__ fromg,
  const float* __restrict__ expa, const float* __restrict__ asum,
  const __hip_bfloat16* __restrict__ rfS, const __hip_bfloat16* __restrict__ gateS,
  float* __restrict__ agg)
{
  __shared__ float P[11720];
  float* w     = P;
  float* rfull = P+700;
  float* gateL = P+1340;
  float* ahead = P+1404;
  float* xe    = P+1416;
  float* hcat  = P+4616;
  float* msgs  = P+7816;
  float* sg    = P+9416;
  const int tid = threadIdx.x;
  const int e = blockIdx.x;
  const int src = ei[e], dst = ei[NE+e];
  const __hip_bfloat16* hs = h + (size_t)src*1600;
  const __hip_bfloat16* hd = h + (size_t)dst*1600;
  for (int idx=tid; idx<700; idx+=256){
    int i = idx/28, j = idx - i*28;
    w[idx] = (j<25) ? wig[(size_t)e*625 + i*25 + j] : 0.f;
  }
  for (int idx=tid; idx<1600; idx+=256){
    int j = idx>>6, c = idx&63;
    hcat[j*128+c]    = __bfloat162float(hs[idx]);
    hcat[j*128+64+c] = __bfloat162float(hd[idx]);
  }
  for (int idx=tid; idx<640; idx+=256) rfull[idx] = __bfloat162float(rfS[(size_t)e*640+idx]);
  if (tid<64) gateL[tid] = silu_f(__bfloat162float(gateS[(size_t)e*64+tid]));
  else if (tid<72) ahead[tid-64] = expa[(size_t)e*8+(tid-64)] / (asum[(size_t)dst*8+(tid-64)] + 1e-8f);
  __syncthreads();
  { // rot1: xe[i][c] = sum_j w[i][j]*hcat[j][c], then scale by r[l(i)][c]
    const int c = tid & 127, ihalf = tid>>7;
    float acc[13];
#pragma unroll
    for (int m=0;m<13;m++) acc[m]=0.f;
    for (int j=0;j<24;j+=4){
      float hv0 = hcat[j*128+c], hv1 = hcat[(j+1)*128+c];
      float hv2 = hcat[(j+2)*128+c], hv3 = hcat[(j+3)*128+c];
#pragma unroll
      for (int m=0;m<13;m++){
        int i = ihalf + 2*m;
        if (i<25){
          const float4 wv = *reinterpret_cast<const float4*>(&w[i*28+j]);
          acc[m] += wv.x*hv0 + wv.y*hv1 + wv.z*hv2 + wv.w*hv3;
        }
      }
    }
    {
      float hv = hcat[24*128+c];
#pragma unroll
      for (int m=0;m<13;m++){ int i=ihalf+2*m; if (i<25) acc[m] += w[i*28+24]*hv; }
    }
#pragma unroll
    for (int m=0;m<13;m++){
      int i = ihalf + 2*m;
      if (i<25){
        int l = (i>=16)?4:((i>=9)?3:((i>=4)?2:((i>=1)?1:0)));
        xe[i*128+c] = acc[m]*rfull[l*128+c];
      }
    }
  }
  __syncthreads();
  { // msg[i][hh] = sum_c xe[i][c]*W1[c][hh]; split K into 2 c-groups, i into 2 halves
    const int hh = tid&63, grp = tid>>6;
    const int cg = grp&1, ihalf = grp>>1;
    const int i0 = ihalf*13;
    float acc[13];
#pragma unroll
    for (int m=0;m<13;m++) acc[m]=0.f;
    for (int cc=0; cc<16; cc++){
      int c = cg*64 + cc*4;
      const float* w1p = W1 + (size_t)c*64 + hh;
      float w10=w1p[0], w11=w1p[64], w12=w1p[128], w13=w1p[192];
#pragma unroll
      for (int m=0;m<13;m++){
        int i = i0+m;
        if (i<25){
          const float4 xv = *reinterpret_cast<const float4*>(&xe[i*128+c]);
          acc[m] += xv.x*w10 + xv.y*w11 + xv.z*w12 + xv.w*w13;
        }
      }
    }
    float* pbuf = hcat;   // hcat dead after rot1
#pragma unroll
    for (int m=0;m<13;m++){
      int i = i0+m;
      if (i<25) pbuf[cg*1600 + i*64 + hh] = acc[m];
    }
  }
  __syncthreads();
  for (int idx=tid; idx<1600; idx+=256) msgs[idx] = hcat[idx] + hcat[1600+idx];
  __syncthreads();
  for (int idx=tid; idx<2304; idx+=256){ // grid fwd + silu
    int g = idx>>6, hh = idx&63;
    float acc=0.f;
#pragma unroll
    for (int i=0;i<25;i++) acc += tog[g*25+i]*msgs[i*64+hh];
    sg[idx] = silu_f(acc);
  }
  __syncthreads();
  for (int idx=tid; idx<1600; idx+=256){ // grid bwd + row0 gate + alpha scale
    int i = idx>>6, hh = idx&63;
    float val;
    if (i==0) val = gateL[hh];
    else {
      val = 0.f;
#pragma unroll
      for (int g=0; g<36; g++) val += fromg[i*36+g]*sg[g*64+hh];
    }
    msgs[idx] = val * ahead[hh>>3];
  }
  __syncthreads();
  { // rot2 (wigner^T) + scatter-add
    float* aggp = agg + (size_t)dst*1600;
    for (int idx=tid; idx<1600; idx+=256){
      int i = idx>>6, c = idx&63;
      float acc=0.f;
#pragma unroll
      for (int j=0;j<25;j++) acc += w[j*28+i]*msgs[j*64+c];
      unsafeAtomicAdd(&aggp[idx], acc);
    }
  }
}

// ---------------- K4: node update + FFN ----------------
// LDS pool: xnew@0(1600) hh2@1600(1600) f1@3200(3200) sgf@6400(4608, alias pbuf)
//           gate@11008(128) invc@11136(64) -> 11200 (44.8 KB)
__global__ __launch_bounds__(256) void k_node(
  const float* __restrict__ x, const float* aggin,
  const float* __restrict__ proj, const float* __restrict__ gamma2,
  const float* __restrict__ glw, const float* __restrict__ glb,
  const float* __restrict__ fw1, const float* __restrict__ fb1,
  const float* __restrict__ fw2, const float* __restrict__ fb2,
  const float* __restrict__ tog, const float* __restrict__ fromg,
  float* out)
{
  __shared__ float P[11200];
  float* xnew = P;
  float* hh2  = P+1600;
  float* f1   = P+3200;
  float* sgf  = P+6400;
  float* gate = P+11008;
  float* invc = P+11136;
  const int tid = threadIdx.x;
  const int n = blockIdx.x;
  for (int idx=tid; idx<1600; idx+=256) sgf[idx] = aggin[(size_t)n*1600+idx];
  __syncthreads();
  for (int idx=tid; idx<1600; idx+=256){ // xnew = x + agg @ proj_out
    int i = idx>>6, c = idx&63;
    float acc = x[(size_t)n*1600+idx];
#pragma unroll 8
    for (int k=0;k<64;k++) acc += sgf[i*64+k]*proj[k*64+c];
    xnew[idx] = acc;
  }
  __syncthreads();
  if (tid<64){
    float ss=0.f;
#pragma unroll
    for (int i=0;i<25;i++){ float v = xnew[i*64+tid]; ss += v*v; }
    invc[tid] = gamma2[tid]*rsqrtf(ss*(1.f/25.f)+1e-6f);
  }
  __syncthreads();
  for (int idx=tid; idx<1600; idx+=256) hh2[idx] = xnew[idx]*invc[idx&63];
  __syncthreads();
  if (tid<128){ // gate = silu(h0 @ gl_w + gl_b)
    float acc = glb[tid];
#pragma unroll 8
    for (int c=0;c<64;c++) acc += hh2[c]*glw[c*128+tid];
    gate[tid] = silu_f(acc);
  }
  { // f1 = h @ ffn_w1 (+b1 on row0); i register-blocked
    const int f = tid&127, ihalf = tid>>7;
    const int i0 = ihalf*13;
    float acc[13];
#pragma unroll
    for (int m=0;m<13;m++) acc[m]=0.f;
    for (int cc=0; cc<16; cc++){
      int c = cc*4;
      const float* wp = fw1 + (size_t)c*128 + f;
      float w0v=wp[0], w1v=wp[128], w2v=wp[256], w3v=wp[384];
#pragma unroll
      for (int m=0;m<13;m++){
        int i = i0+m;
        if (i<25){
          const float4 hv = *reinterpret_cast<const float4*>(&hh2[i*64+c]);
          acc[m] += hv.x*w0v + hv.y*w1v + hv.z*w2v + hv.w*w3v;
        }
      }
    }
    float b = fb1[f];
#pragma unroll
    for (int m=0;m<13;m++){
      int i = i0+m;
      if (i<25) f1[i*128+f] = acc[m] + (i==0 ? b : 0.f);
    }
  }
  __syncthreads();
  for (int idx=tid; idx<4608; idx+=256){ // grid fwd + silu (F=128)
    int g = idx>>7, f = idx&127;
    float acc=0.f;
#pragma unroll
    for (int i=0;i<25;i++) acc += tog[g*25+i]*f1[i*128+f];
    sgf[idx] = silu_f(acc);
  }
  __syncthreads();
  for (int idx=tid; idx<3200; idx+=256){ // grid bwd + row0 gate
    int i = idx>>7, f = idx&127;
    float val;
    if (i==0) val = gate[f];
    else {
      val = 0.f;
#pragma unroll
      for (int g=0;g<36;g++) val += fromg[i*36+g]*sgf[g*128+f];
    }
    f1[idx] = val;
  }
  __syncthreads();
  { // f2 = f1a @ ffn_w2 ; split K(128) into 2 f-groups, i into halves
    const int c = tid&63, grp = tid>>6;
    const int fg = grp&1, ihalf = grp>>1;
    const int i0 = ihalf*13;
    float acc[13];
#pragma unroll
    for (int m=0;m<13;m++) acc[m]=0.f;
    for (int ff=0; ff<16; ff++){
      int fidx = fg*64 + ff*4;
      const float* wp = fw2 + (size_t)fidx*64 + c;
      float w0v=wp[0], w1v=wp[64], w2v=wp[128], w3v=wp[192];
#pragma unroll
      for (int m=0;m<13;m++){
        int i = i0+m;
        if (i<25){
          const float4 fv = *reinterpret_cast<const float4*>(&f1[i*128+fidx]);
          acc[m] += fv.x*w0v + fv.y*w1v + fv.z*w2v + fv.w*w3v;
        }
      }
    }
    float* pbuf = sgf;  // sgf dead after grid bwd
#pragma unroll
    for (int m=0;m<13;m++){
      int i = i0+m;
      if (i<25) pbuf[fg*1600 + i*64 + c] = acc[m];
    }
  }
  __syncthreads();
  for (int idx=tid; idx<1600; idx+=256){
    int i = idx>>6, c = idx&63;
    float acc = sgf[idx] + sgf[1600+idx] + (i==0 ? fb2[c] : 0.f);
    out[(size_t)n*1600+idx] = xnew[idx] + acc;
  }
}

extern "C" void kernel_launch(void* const* d_in, const int* in_sizes, int n_in,
                              void* d_out, int out_size, void* d_ws, size_t ws_size,
                              hipStream_t stream) {
  (void)in_sizes; (void)n_in; (void)ws_size;
  const float* x     = (const float*)d_in[0];
  const int*   ei    = (const int*)d_in[1];
  const int*   an    = (const int*)d_in[2];
  const float* edist = (const float*)d_in[3];
  const float* wig   = (const float*)d_in[4];
  const float* stab  = (const float*)d_in[5];
  const float* ttab  = (const float*)d_in[6];
  const float* rw1   = (const float*)d_in[7];
  const float* rb1   = (const float*)d_in[8];
  const float* rw2   = (const float*)d_in[9];
  const float* rb2   = (const float*)d_in[10];
  const float* rw3   = (const float*)d_in[11];
  const float* rb3   = (const float*)d_in[12];
  const float* W1    = (const float*)d_in[13];
  const float* w0e   = (const float*)d_in[14];
  const float* adot  = (const float*)d_in[15];
  const float* tog   = (const float*)d_in[16];
  const float* fromg = (const float*)d_in[17];
  const float* proj  = (const float*)d_in[18];
  const float* g1    = (const float*)d_in[19];
  const float* g2    = (const float*)d_in[20];
  const float* glw   = (const float*)d_in[21];
  const float* glb   = (const float*)d_in[22];
  const float* fw1   = (const float*)d_in[23];
  const float* fb1   = (const float*)d_in[24];
  const float* fw2   = (const float*)d_in[25];
  const float* fb2   = (const float*)d_in[26];
  float* out = (float*)d_out;

  // workspace layout (bytes, 16-aligned):
  char* wsb = (char*)d_ws;
  __hip_bfloat16* hbuf  = (__hip_bfloat16*)(wsb);               // N*1600 bf16 = 32,000,000
  __hip_bfloat16* rfS   = (__hip_bfloat16*)(wsb + 32000000);    // E*640 bf16  = 64,000,000
  __hip_bfloat16* gateS = (__hip_bfloat16*)(wsb + 96000000);    // E*64 bf16   =  6,400,000
  float*          expa  = (float*)(wsb + 102400000);            // E*8 f32     =  1,600,000
  float*          asum  = (float*)(wsb + 104000000);            // N*8 f32     =    320,000

  hipMemsetAsync(asum, 0, (size_t)NN*8*sizeof(float), stream);
  hipMemsetAsync(d_out, 0, (size_t)out_size*sizeof(float), stream);  // d_out doubles as agg

  k_rms1 <<<(NN*64+255)/256, 256, 0, stream>>>(x, g1, hbuf);
  k_alpha<<<NE/16, 256, 0, stream>>>(hbuf, ei, an, edist, wig, stab, ttab,
                                     rw1, rb1, rw2, rb2, rw3, rb3, w0e, adot,
                                     expa, asum, rfS, gateS);
  k_edge <<<NE, 256, 0, stream>>>(hbuf, ei, wig, W1, tog, fromg,
                                  expa, asum, rfS, gateS, out);
  k_node <<<NN, 256, 0, stream>>>(x, out, proj, g2, glw, glb,
                                  fw1, fb1, fw2, fb2, tog, fromg, out);
}

// Round 2
// 1973.422 us; speedup vs baseline: 1.7654x; 1.7654x over previous
//
#include <hip/hip_runtime.h>
#include <hip/hip_bf16.h>

#define NN 10000
#define NE 50000

typedef __attribute__((ext_vector_type(8))) short bfrag8;  // 8 bf16 = 4 VGPR (MFMA A/B)
typedef __attribute__((ext_vector_type(4))) short s16x4;   // 4 bf16 = b64 store
typedef __attribute__((ext_vector_type(4))) float f32x4;   // MFMA C/D

__device__ __forceinline__ float silu_f(float v){ return v / (1.0f + __expf(-v)); }
__device__ __forceinline__ short f2b(float f){           // f32 -> bf16 RNE
  unsigned u = __float_as_uint(f);
  u += 0x7fffu + ((u>>16)&1u);
  return (short)(u>>16);
}
__device__ __forceinline__ float b2f(short s){
  return __uint_as_float(((unsigned)(unsigned short)s)<<16);
}

// ---------------- K0: h = rmsnorm(x, gamma1) -> bf16 ----------------
__global__ __launch_bounds__(256) void k_rms1(const float* __restrict__ x,
                                              const float* __restrict__ gamma,
                                              __hip_bfloat16* __restrict__ h){
  int idx = blockIdx.x*256 + threadIdx.x;
  if (idx >= NN*64) return;
  int n = idx>>6, c = idx&63;
  const float* xp = x + (size_t)n*1600 + c;
  float ss = 0.f;
#pragma unroll
  for (int i=0;i<25;i++){ float v = xp[i*64]; ss += v*v; }
  float inv = gamma[c] * rsqrtf(ss*(1.f/25.f) + 1e-6f);
  __hip_bfloat16* hp = h + (size_t)n*1600 + c;
#pragma unroll
  for (int i=0;i<25;i++) hp[i*64] = __float2bfloat16(xp[i*64]*inv);
}

// ------------- Kprep: weights -> MFMA-padded bf16 layouts -------------
// w1t  = W1^T  [h=64][k=c, stride 136]  (cols>=128 zero)
// togA = to_grid [g=48][k=i, stride 40] (g>=36 or i>=25 zero)
// fgA  = from_grid [j=32][k=g, stride 72] (j>=25 or g>=36 zero)
__global__ void k_wprep(const float* __restrict__ W1, const float* __restrict__ tog,
                        const float* __restrict__ fromg,
                        short* __restrict__ w1t, short* __restrict__ togA,
                        short* __restrict__ fgA){
  int t0 = blockIdx.x*blockDim.x + threadIdx.x;
  int stride = gridDim.x*blockDim.x;
  for (int idx=t0; idx<64*136; idx+=stride){
    int hh = idx/136, k = idx-136*hh;
    w1t[idx] = (k<128) ? f2b(W1[k*64+hh]) : (short)0;
  }
  for (int idx=t0; idx<48*40; idx+=stride){
    int g = idx/40, i = idx-40*g;
    togA[idx] = (g<36 && i<25) ? f2b(tog[g*25+i]) : (short)0;
  }
  for (int idx=t0; idx<32*72; idx+=stride){
    int j = idx/72, g = idx-72*j;
    fgA[idx] = (j<25 && g<36) ? f2b(fromg[j*36+g]) : (short)0;
  }
}

// ---------------- K1: radial MLP + alpha/gate per edge (unchanged) ----------------
__global__ __launch_bounds__(256) void k_alpha(
  const __hip_bfloat16* __restrict__ h, const int* __restrict__ ei,
  const int* __restrict__ an, const float* __restrict__ edist,
  const float* __restrict__ wig, const float* __restrict__ stab,
  const float* __restrict__ ttab,
  const float* __restrict__ rw1, const float* __restrict__ rb1,
  const float* __restrict__ rw2, const float* __restrict__ rb2,
  const float* __restrict__ rw3, const float* __restrict__ rb3,
  const float* __restrict__ w0e, const float* __restrict__ adot,
  float* __restrict__ expa, float* __restrict__ asum,
  __hip_bfloat16* __restrict__ rfS, __hip_bfloat16* __restrict__ gateS)
{
  __shared__ float S4[4][1152];
  const int wv = threadIdx.x>>6, lane = threadIdx.x&63;
  float* S = S4[wv];
  for (int sub=0; sub<4; ++sub){
    const int e = blockIdx.x*16 + sub*4 + wv;
    const int src = ei[e], dst = ei[NE+e];
    if (lane<32){
      S[lane]    = edist[(size_t)e*32 + lane];
      S[64+lane] = ttab[(size_t)an[dst]*32 + lane];
    } else {
      S[lane]    = stab[(size_t)an[src]*32 + (lane-32)];
    }
    if (lane<25) S[992+lane] = wig[(size_t)e*625 + lane];
    __syncthreads();
    { float a = rb1[lane];
#pragma unroll 8
      for (int k=0;k<96;k++) a += S[k]*rw1[k*64+lane];
      S[96+lane] = silu_f(a); }
    __syncthreads();
    { float a = rb2[lane];
#pragma unroll 8
      for (int k=0;k<64;k++) a += S[96+k]*rw2[k*64+lane];
      S[160+lane] = silu_f(a); }
    __syncthreads();
    { float acc[10];
#pragma unroll
      for (int m=0;m<10;m++) acc[m] = rb3[lane + 64*m];
      for (int k=0;k<64;k++){
        float rv = S[160+k];
        const float* wp = rw3 + (size_t)k*640 + lane;
#pragma unroll
        for (int m=0;m<10;m++) acc[m] += rv*wp[64*m];
      }
#pragma unroll
      for (int m=0;m<10;m++){
        S[224 + lane + 64*m] = acc[m];
        rfS[(size_t)e*640 + lane + 64*m] = __float2bfloat16(acc[m]);
      } }
    { const __hip_bfloat16* hs = h + (size_t)src*1600;
      const __hip_bfloat16* hd = h + (size_t)dst*1600;
      float xs=0.f, xd=0.f;
#pragma unroll
      for (int j=0;j<25;j++){
        float w0 = S[992+j];
        xs += w0*__bfloat162float(hs[j*64+lane]);
        xd += w0*__bfloat162float(hd[j*64+lane]);
      }
      S[864+lane]    = xs*S[224+lane];
      S[864+64+lane] = xd*S[224+64+lane]; }
    __syncthreads();
    { float f0=0.f, f1=0.f, g=0.f;
#pragma unroll 8
      for (int c=0;c<128;c++){
        float xv = S[864+c];
        const float* wp = w0e + (size_t)c*192;
        f0 += xv*wp[lane];
        f1 += xv*wp[64+lane];
        g  += xv*wp[128+lane];
      }
      S[1024+lane]    = silu_f(f0)*adot[lane];
      S[1024+64+lane] = silu_f(f1)*adot[64+lane];
      gateS[(size_t)e*64+lane] = __float2bfloat16(g); }
    __syncthreads();
    if (lane<8){
      float s=0.f;
#pragma unroll
      for (int a=0;a<16;a++) s += S[1024+lane*16+a];
      float ea = __expf(s);
      expa[(size_t)e*8+lane] = ea;
      unsafeAtomicAdd(&asum[(size_t)dst*8+lane], ea);
    }
    __syncthreads();
  }
}

// ---------------- K3: MFMA edge kernel ----------------
// 1 edge/block, 4 waves. GEMM chain designed so each stage's output M-dim is
// the next stage's K-dim: D-frag (col=lane&15, 4 consecutive rows) writes are
// k-contiguous ds_write_b64; all A/B frag reads are contiguous ds_read_b128.
// POOL (shorts): hcatT@0[128][40] (aliased by sgB[64][72])  wA@5120[32][40]
//   wT@6400[32][40]  xeB@7680[32][136] (aliased by msgs2B[64][40])
//   msgsB@12032[64][40]  rfull(f32)@14592[640]  gateL(f32)@15872[64]
//   ahead(f32)@16000[8]  -> 16032 shorts = 32064 B -> 5 blocks/CU by LDS
__global__ __launch_bounds__(256,4) void k_edge(
  const __hip_bfloat16* __restrict__ h, const int* __restrict__ ei,
  const float* __restrict__ wig,
  const short* __restrict__ w1t, const short* __restrict__ togA,
  const short* __restrict__ fgA,
  const float* __restrict__ expa, const float* __restrict__ asum,
  const __hip_bfloat16* __restrict__ rfS, const __hip_bfloat16* __restrict__ gateS,
  float* __restrict__ agg)
{
  __shared__ __align__(16) short POOL[16032];
  float* rfull = (float*)&POOL[14592];
  float* gateL = (float*)&POOL[15872];
  float* ahead = (float*)&POOL[16000];
  const int tid = threadIdx.x;
  const int wv = tid>>6, lane = tid&63, lo = lane&15, q = lane>>4;
  const int e = blockIdx.x;
  const int src = ei[e], dst = ei[NE+e];

  { // zero hcatT+wA+wT (shorts [0,7680) = 960 int4) -> K-padding correctness
    int4 z; z.x=0; z.y=0; z.z=0; z.w=0;
    int4* zp = (int4*)POOL;
    for (int idx=tid; idx<960; idx+=256) zp[idx] = z;
  }
  __syncthreads();
  // stage wigner -> wA [i][j], wT [i][j]=W[j][i], bf16
  for (int idx=tid; idx<625; idx+=256){
    int i = idx/25, j = idx-25*i;
    short v = f2b(wig[(size_t)e*625+idx]);
    POOL[5120 + i*40 + j] = v;
    POOL[6400 + j*40 + i] = v;
  }
  { // stage hcatT [c 0..127][j 0..24]: transpose of gathered h rows
    const __hip_bfloat16* hs = h + (size_t)src*1600;
    const __hip_bfloat16* hd = h + (size_t)dst*1600;
    for (int idx=tid; idx<400; idx+=256){
      int nh = idx/200, rem = idx-200*nh;
      int j = rem>>3, cg = rem&7;
      const __hip_bfloat16* hp = nh ? hd : hs;
      uint4 v = *(const uint4*)(hp + j*64 + cg*8);
      unsigned el[8] = {v.x&0xffffu, v.x>>16, v.y&0xffffu, v.y>>16,
                        v.z&0xffffu, v.z>>16, v.w&0xffffu, v.w>>16};
      int cb = nh*64 + cg*8;
#pragma unroll
      for (int qq=0;qq<8;qq++) POOL[(cb+qq)*40 + j] = (short)el[qq];
    }
  }
  for (int idx=tid; idx<640; idx+=256) rfull[idx] = __bfloat162float(rfS[(size_t)e*640+idx]);
  if (tid<64) gateL[tid] = silu_f(__bfloat162float(gateS[(size_t)e*64+tid]));
  else if (tid<72) ahead[tid-64] = expa[(size_t)e*8+(tid-64)] / (asum[(size_t)dst*8+(tid-64)] + 1e-8f);
  __syncthreads();

  { // rot1: xe[i][c] = sum_j W[i][j] hcat[j][c], *r.  M=c(128), N=i(32), K=j(32)
    f32x4 zf = {0.f,0.f,0.f,0.f};
    f32x4 acc[2][2] = {{zf,zf},{zf,zf}};
    bfrag8 b0 = *(const bfrag8*)&POOL[5120 + (lo)*40 + q*8];
    bfrag8 b1 = *(const bfrag8*)&POOL[5120 + (16+lo)*40 + q*8];
#pragma unroll
    for (int t=0;t<2;t++){
      int mrow = (2*wv+t)*16 + lo;           // c
      bfrag8 a = *(const bfrag8*)&POOL[mrow*40 + q*8];
      acc[t][0] = __builtin_amdgcn_mfma_f32_16x16x32_bf16(a, b0, acc[t][0], 0,0,0);
      acc[t][1] = __builtin_amdgcn_mfma_f32_16x16x32_bf16(a, b1, acc[t][1], 0,0,0);
    }
#pragma unroll
    for (int t=0;t<2;t++){
      int c0 = (2*wv+t)*16 + q*4;
#pragma unroll
      for (int nt=0;nt<2;nt++){
        int i = nt*16 + lo;
        int l = (i>=16)?4:((i>=9)?3:((i>=4)?2:((i>=1)?1:0)));
        const f32x4 rv = *(const f32x4*)&rfull[l*128 + c0];
        s16x4 o;
#pragma unroll
        for (int r=0;r<4;r++) o[r] = f2b(acc[t][nt][r]*rv[r]);
        *(s16x4*)&POOL[7680 + i*136 + c0] = o;       // xeB [i][c]
      }
    }
  }
  __syncthreads();

  { // msg: msgs[i][h] = sum_c xe[i][c] W1[c][h].  M=i(32), N=h(64), K=c(128)
    const int hh = wv*16 + lo;
    f32x4 zf = {0.f,0.f,0.f,0.f};
    f32x4 acc[2] = {zf,zf};
#pragma unroll
    for (int kt=0;kt<4;kt++){
      bfrag8 b = *(const bfrag8*)&w1t[hh*136 + kt*32 + q*8];   // global, L1-hot
#pragma unroll
      for (int t=0;t<2;t++){
        bfrag8 a = *(const bfrag8*)&POOL[7680 + (t*16+lo)*136 + kt*32 + q*8];
        acc[t] = __builtin_amdgcn_mfma_f32_16x16x32_bf16(a, b, acc[t], 0,0,0);
      }
    }
#pragma unroll
    for (int t=0;t<2;t++){
      s16x4 o;
#pragma unroll
      for (int r=0;r<4;r++) o[r] = f2b(acc[t][r]);
      *(s16x4*)&POOL[12032 + hh*40 + t*16 + q*4] = o;          // msgsB [h][i]
    }
  }
  __syncthreads();

  { // grid fwd: sg[g][h] = silu(sum_i to_grid[g][i] msgs[i][h]). M=g(48),N=h,K=i(32)
    const int hh = wv*16 + lo;
    bfrag8 b = *(const bfrag8*)&POOL[12032 + hh*40 + q*8];
    f32x4 zf = {0.f,0.f,0.f,0.f};
    f32x4 acc[3] = {zf,zf,zf};
#pragma unroll
    for (int t=0;t<3;t++){
      bfrag8 a = *(const bfrag8*)&togA[(t*16+lo)*40 + q*8];    // global
      acc[t] = __builtin_amdgcn_mfma_f32_16x16x32_bf16(a, b, acc[t], 0,0,0);
    }
#pragma unroll
    for (int t=0;t<3;t++){
      s16x4 o;
#pragma unroll
      for (int r=0;r<4;r++) o[r] = f2b(silu_f(acc[t][r]));
      *(s16x4*)&POOL[hh*72 + t*16 + q*4] = o;                  // sgB [h][g] (aliases hcatT)
    }
  }
  __syncthreads();

  { // grid bwd: xg[j][h] = sum_g from_grid[j][g] sg[g][h]; row0<-gate; *alpha.
    // M=j(32), N=h, K=g(64; cols>=36 zero on A side)
    const int hh = wv*16 + lo;
    f32x4 zf = {0.f,0.f,0.f,0.f};
    f32x4 acc[2] = {zf,zf};
#pragma unroll
    for (int kt=0;kt<2;kt++){
      bfrag8 b = *(const bfrag8*)&POOL[hh*72 + kt*32 + q*8];
#pragma unroll
      for (int t=0;t<2;t++){
        bfrag8 a = *(const bfrag8*)&fgA[(t*16+lo)*72 + kt*32 + q*8];  // global
        acc[t] = __builtin_amdgcn_mfma_f32_16x16x32_bf16(a, b, acc[t], 0,0,0);
      }
    }
    float ah = ahead[hh>>3];
#pragma unroll
    for (int t=0;t<2;t++){
      s16x4 o;
#pragma unroll
      for (int r=0;r<4;r++){
        int j = t*16 + q*4 + r;
        float v = acc[t][r];
        if (j==0) v = gateL[hh];
        o[r] = f2b(v*ah);
      }
      *(s16x4*)&POOL[7680 + hh*40 + t*16 + q*4] = o;           // msgs2B [h][j] (aliases xeB)
    }
  }
  __syncthreads();

  { // rot2: out[i][h] = sum_j W[j][i] msgs2[j][h].  M=i(32), N=h, K=j(32)
    const int hh = wv*16 + lo;
    bfrag8 b = *(const bfrag8*)&POOL[7680 + hh*40 + q*8];
    f32x4 zf = {0.f,0.f,0.f,0.f};
    f32x4 acc[2] = {zf,zf};
#pragma unroll
    for (int t=0;t<2;t++){
      bfrag8 a = *(const bfrag8*)&POOL[6400 + (t*16+lo)*40 + q*8];   // wT
      acc[t] = __builtin_amdgcn_mfma_f32_16x16x32_bf16(a, b, acc[t], 0,0,0);
    }
    float* aggp = agg + (size_t)dst*1600;
#pragma unroll
    for (int t=0;t<2;t++){
#pragma unroll
      for (int r=0;r<4;r++){
        int i = t*16 + q*4 + r;
        if (i<25) unsafeAtomicAdd(&aggp[i*64+hh], acc[t][r]);
      }
    }
  }
}

// ---------------- K4: node update + FFN (unchanged) ----------------
__global__ __launch_bounds__(256) void k_node(
  const float* __restrict__ x, const float* aggin,
  const float* __restrict__ proj, const float* __restrict__ gamma2,
  const float* __restrict__ glw, const float* __restrict__ glb,
  const float* __restrict__ fw1, const float* __restrict__ fb1,
  const float* __restrict__ fw2, const float* __restrict__ fb2,
  const float* __restrict__ tog, const float* __restrict__ fromg,
  float* out)
{
  __shared__ float P[11200];
  float* xnew = P;
  float* hh2  = P+1600;
  float* f1   = P+3200;
  float* sgf  = P+6400;
  float* gate = P+11008;
  float* invc = P+11136;
  const int tid = threadIdx.x;
  const int n = blockIdx.x;
  for (int idx=tid; idx<1600; idx+=256) sgf[idx] = aggin[(size_t)n*1600+idx];
  __syncthreads();
  for (int idx=tid; idx<1600; idx+=256){
    int i = idx>>6, c = idx&63;
    float acc = x[(size_t)n*1600+idx];
#pragma unroll 8
    for (int k=0;k<64;k++) acc += sgf[i*64+k]*proj[k*64+c];
    xnew[idx] = acc;
  }
  __syncthreads();
  if (tid<64){
    float ss=0.f;
#pragma unroll
    for (int i=0;i<25;i++){ float v = xnew[i*64+tid]; ss += v*v; }
    invc[tid] = gamma2[tid]*rsqrtf(ss*(1.f/25.f)+1e-6f);
  }
  __syncthreads();
  for (int idx=tid; idx<1600; idx+=256) hh2[idx] = xnew[idx]*invc[idx&63];
  __syncthreads();
  if (tid<128){
    float acc = glb[tid];
#pragma unroll 8
    for (int c=0;c<64;c++) acc += hh2[c]*glw[c*128+tid];
    gate[tid] = silu_f(acc);
  }
  {
    const int f = tid&127, ihalf = tid>>7;
    const int i0 = ihalf*13;
    float acc[13];
#pragma unroll
    for (int m=0;m<13;m++) acc[m]=0.f;
    for (int cc=0; cc<16; cc++){
      int c = cc*4;
      const float* wp = fw1 + (size_t)c*128 + f;
      float w0v=wp[0], w1v=wp[128], w2v=wp[256], w3v=wp[384];
#pragma unroll
      for (int m=0;m<13;m++){
        int i = i0+m;
        if (i<25){
          const float4 hv = *reinterpret_cast<const float4*>(&hh2[i*64+c]);
          acc[m] += hv.x*w0v + hv.y*w1v + hv.z*w2v + hv.w*w3v;
        }
      }
    }
    float b = fb1[f];
#pragma unroll
    for (int m=0;m<13;m++){
      int i = i0+m;
      if (i<25) f1[i*128+f] = acc[m] + (i==0 ? b : 0.f);
    }
  }
  __syncthreads();
  for (int idx=tid; idx<4608; idx+=256){
    int g = idx>>7, f = idx&127;
    float acc=0.f;
#pragma unroll
    for (int i=0;i<25;i++) acc += tog[g*25+i]*f1[i*128+f];
    sgf[idx] = silu_f(acc);
  }
  __syncthreads();
  for (int idx=tid; idx<3200; idx+=256){
    int i = idx>>7, f = idx&127;
    float val;
    if (i==0) val = gate[f];
    else {
      val = 0.f;
#pragma unroll
      for (int g=0;g<36;g++) val += fromg[i*36+g]*sgf[g*128+f];
    }
    f1[idx] = val;
  }
  __syncthreads();
  {
    const int c = tid&63, grp = tid>>6;
    const int fg = grp&1, ihalf = grp>>1;
    const int i0 = ihalf*13;
    float acc[13];
#pragma unroll
    for (int m=0;m<13;m++) acc[m]=0.f;
    for (int ff=0; ff<16; ff++){
      int fidx = fg*64 + ff*4;
      const float* wp = fw2 + (size_t)fidx*64 + c;
      float w0v=wp[0], w1v=wp[64], w2v=wp[128], w3v=wp[192];
#pragma unroll
      for (int m=0;m<13;m++){
        int i = i0+m;
        if (i<25){
          const float4 fv = *reinterpret_cast<const float4*>(&f1[i*128+fidx]);
          acc[m] += fv.x*w0v + fv.y*w1v + fv.z*w2v + fv.w*w3v;
        }
      }
    }
    float* pbuf = sgf;
#pragma unroll
    for (int m=0;m<13;m++){
      int i = i0+m;
      if (i<25) pbuf[fg*1600 + i*64 + c] = acc[m];
    }
  }
  __syncthreads();
  for (int idx=tid; idx<1600; idx+=256){
    int i = idx>>6, c = idx&63;
    float acc = sgf[idx] + sgf[1600+idx] + (i==0 ? fb2[c] : 0.f);
    out[(size_t)n*1600+idx] = xnew[idx] + acc;
  }
}

extern "C" void kernel_launch(void* const* d_in, const int* in_sizes, int n_in,
                              void* d_out, int out_size, void* d_ws, size_t ws_size,
                              hipStream_t stream) {
  (void)in_sizes; (void)n_in; (void)ws_size;
  const float* x     = (const float*)d_in[0];
  const int*   ei    = (const int*)d_in[1];
  const int*   an    = (const int*)d_in[2];
  const float* edist = (const float*)d_in[3];
  const float* wig   = (const float*)d_in[4];
  const float* stab  = (const float*)d_in[5];
  const float* ttab  = (const float*)d_in[6];
  const float* rw1   = (const float*)d_in[7];
  const float* rb1   = (const float*)d_in[8];
  const float* rw2   = (const float*)d_in[9];
  const float* rb2   = (const float*)d_in[10];
  const float* rw3   = (const float*)d_in[11];
  const float* rb3   = (const float*)d_in[12];
  const float* W1    = (const float*)d_in[13];
  const float* w0e   = (const float*)d_in[14];
  const float* adot  = (const float*)d_in[15];
  const float* tog   = (const float*)d_in[16];
  const float* fromg = (const float*)d_in[17];
  const float* proj  = (const float*)d_in[18];
  const float* g1    = (const float*)d_in[19];
  const float* g2    = (const float*)d_in[20];
  const float* glw   = (const float*)d_in[21];
  const float* glb   = (const float*)d_in[22];
  const float* fw1   = (const float*)d_in[23];
  const float* fb1   = (const float*)d_in[24];
  const float* fw2   = (const float*)d_in[25];
  const float* fb2   = (const float*)d_in[26];
  float* out = (float*)d_out;

  char* wsb = (char*)d_ws;
  __hip_bfloat16* hbuf  = (__hip_bfloat16*)(wsb);               // N*1600 bf16
  __hip_bfloat16* rfS   = (__hip_bfloat16*)(wsb + 32000000);    // E*640 bf16
  __hip_bfloat16* gateS = (__hip_bfloat16*)(wsb + 96000000);    // E*64 bf16
  float*          expa  = (float*)(wsb + 102400000);            // E*8 f32
  float*          asum  = (float*)(wsb + 104000000);            // N*8 f32
  short*          w1t   = (short*)(wsb + 104320000);            // 64*136 bf16
  short*          togA  = (short*)(wsb + 104337408);            // 48*40 bf16
  short*          fgA   = (short*)(wsb + 104341248);            // 32*72 bf16

  hipMemsetAsync(asum, 0, (size_t)NN*8*sizeof(float), stream);
  hipMemsetAsync(d_out, 0, (size_t)out_size*sizeof(float), stream);  // d_out = agg

  k_wprep<<<32, 256, 0, stream>>>(W1, tog, fromg, w1t, togA, fgA);
  k_rms1 <<<(NN*64+255)/256, 256, 0, stream>>>(x, g1, hbuf);
  k_alpha<<<NE/16, 256, 0, stream>>>(hbuf, ei, an, edist, wig, stab, ttab,
                                     rw1, rb1, rw2, rb2, rw3, rb3, w0e, adot,
                                     expa, asum, rfS, gateS);
  k_edge <<<NE, 256, 0, stream>>>(hbuf, ei, wig, w1t, togA, fgA,
                                  expa, asum, rfS, gateS, out);
  k_node <<<NN, 256, 0, stream>>>(x, out, proj, g2, glw, glb,
                                  fw1, fb1, fw2, fb2, tog, fromg, out);
}

// Round 3
// 1348.490 us; speedup vs baseline: 2.5835x; 1.4634x over previous
//
#include <hip/hip_runtime.h>
#include <hip/hip_bf16.h>

#define NN 10000
#define NE 50000

typedef __attribute__((ext_vector_type(8))) short bfrag8;  // 8 bf16 = 4 VGPR (MFMA A/B)
typedef __attribute__((ext_vector_type(4))) short s16x4;   // 4 bf16 = b64 store
typedef __attribute__((ext_vector_type(4))) float f32x4;   // MFMA C/D

__device__ __forceinline__ float silu_f(float v){ return v / (1.0f + __expf(-v)); }
__device__ __forceinline__ short f2b(float f){           // f32 -> bf16 RNE
  unsigned u = __float_as_uint(f);
  u += 0x7fffu + ((u>>16)&1u);
  return (short)(u>>16);
}

// ---------------- K0: h = rmsnorm(x, gamma1) -> bf16 ----------------
__global__ __launch_bounds__(256) void k_rms1(const float* __restrict__ x,
                                              const float* __restrict__ gamma,
                                              __hip_bfloat16* __restrict__ h){
  int idx = blockIdx.x*256 + threadIdx.x;
  if (idx >= NN*64) return;
  int n = idx>>6, c = idx&63;
  const float* xp = x + (size_t)n*1600 + c;
  float ss = 0.f;
#pragma unroll
  for (int i=0;i<25;i++){ float v = xp[i*64]; ss += v*v; }
  float inv = gamma[c] * rsqrtf(ss*(1.f/25.f) + 1e-6f);
  __hip_bfloat16* hp = h + (size_t)n*1600 + c;
#pragma unroll
  for (int i=0;i<25;i++) hp[i*64] = __float2bfloat16(xp[i*64]*inv);
}

// ------------- Kprep: weights -> MFMA bf16 layouts -------------
__global__ void k_wprep(const float* __restrict__ W1, const float* __restrict__ tog,
                        const float* __restrict__ fromg, const float* __restrict__ proj,
                        const float* __restrict__ fw1, const float* __restrict__ fw2,
                        short* __restrict__ w1t, short* __restrict__ togA,
                        short* __restrict__ fgA, short* __restrict__ projT,
                        short* __restrict__ fw1T, short* __restrict__ fw2T){
  int t0 = blockIdx.x*blockDim.x + threadIdx.x;
  int stride = gridDim.x*blockDim.x;
  for (int idx=t0; idx<64*136; idx+=stride){
    int hh = idx/136, k = idx-136*hh;
    w1t[idx] = (k<128) ? f2b(W1[k*64+hh]) : (short)0;
  }
  for (int idx=t0; idx<48*40; idx+=stride){
    int g = idx/40, i = idx-40*g;
    togA[idx] = (g<36 && i<25) ? f2b(tog[g*25+i]) : (short)0;
  }
  for (int idx=t0; idx<32*72; idx+=stride){
    int j = idx/72, g = idx-72*j;
    fgA[idx] = (j<25 && g<36) ? f2b(fromg[j*36+g]) : (short)0;
  }
  for (int idx=t0; idx<64*64; idx+=stride){   // projT[c][k] = proj[k][c]
    int c = idx>>6, k = idx&63;
    projT[idx] = f2b(proj[k*64+c]);
  }
  for (int idx=t0; idx<128*64; idx+=stride){  // fw1T[f][c] = fw1[c][f]
    int f = idx>>6, c = idx&63;
    fw1T[idx] = f2b(fw1[c*128+f]);
  }
  for (int idx=t0; idx<64*128; idx+=stride){  // fw2T[c][f] = fw2[f][c]
    int c = idx>>7, f = idx&127;
    fw2T[idx] = f2b(fw2[f*64+c]);
  }
}

// ---------------- K1: radial MLP + alpha/gate per edge (unchanged) ----------------
__global__ __launch_bounds__(256) void k_alpha(
  const __hip_bfloat16* __restrict__ h, const int* __restrict__ ei,
  const int* __restrict__ an, const float* __restrict__ edist,
  const float* __restrict__ wig, const float* __restrict__ stab,
  const float* __restrict__ ttab,
  const float* __restrict__ rw1, const float* __restrict__ rb1,
  const float* __restrict__ rw2, const float* __restrict__ rb2,
  const float* __restrict__ rw3, const float* __restrict__ rb3,
  const float* __restrict__ w0e, const float* __restrict__ adot,
  float* __restrict__ expa, float* __restrict__ asum,
  __hip_bfloat16* __restrict__ rfS, __hip_bfloat16* __restrict__ gateS)
{
  __shared__ float S4[4][1152];
  const int wv = threadIdx.x>>6, lane = threadIdx.x&63;
  float* S = S4[wv];
  for (int sub=0; sub<4; ++sub){
    const int e = blockIdx.x*16 + sub*4 + wv;
    const int src = ei[e], dst = ei[NE+e];
    if (lane<32){
      S[lane]    = edist[(size_t)e*32 + lane];
      S[64+lane] = ttab[(size_t)an[dst]*32 + lane];
    } else {
      S[lane]    = stab[(size_t)an[src]*32 + (lane-32)];
    }
    if (lane<25) S[992+lane] = wig[(size_t)e*625 + lane];
    __syncthreads();
    { float a = rb1[lane];
#pragma unroll 8
      for (int k=0;k<96;k++) a += S[k]*rw1[k*64+lane];
      S[96+lane] = silu_f(a); }
    __syncthreads();
    { float a = rb2[lane];
#pragma unroll 8
      for (int k=0;k<64;k++) a += S[96+k]*rw2[k*64+lane];
      S[160+lane] = silu_f(a); }
    __syncthreads();
    { float acc[10];
#pragma unroll
      for (int m=0;m<10;m++) acc[m] = rb3[lane + 64*m];
      for (int k=0;k<64;k++){
        float rv = S[160+k];
        const float* wp = rw3 + (size_t)k*640 + lane;
#pragma unroll
        for (int m=0;m<10;m++) acc[m] += rv*wp[64*m];
      }
#pragma unroll
      for (int m=0;m<10;m++){
        S[224 + lane + 64*m] = acc[m];
        rfS[(size_t)e*640 + lane + 64*m] = __float2bfloat16(acc[m]);
      } }
    { const __hip_bfloat16* hs = h + (size_t)src*1600;
      const __hip_bfloat16* hd = h + (size_t)dst*1600;
      float xs=0.f, xd=0.f;
#pragma unroll
      for (int j=0;j<25;j++){
        float w0 = S[992+j];
        xs += w0*__bfloat162float(hs[j*64+lane]);
        xd += w0*__bfloat162float(hd[j*64+lane]);
      }
      S[864+lane]    = xs*S[224+lane];
      S[864+64+lane] = xd*S[224+64+lane]; }
    __syncthreads();
    { float f0=0.f, f1=0.f, g=0.f;
#pragma unroll 8
      for (int c=0;c<128;c++){
        float xv = S[864+c];
        const float* wp = w0e + (size_t)c*192;
        f0 += xv*wp[lane];
        f1 += xv*wp[64+lane];
        g  += xv*wp[128+lane];
      }
      S[1024+lane]    = silu_f(f0)*adot[lane];
      S[1024+64+lane] = silu_f(f1)*adot[64+lane];
      gateS[(size_t)e*64+lane] = __float2bfloat16(g); }
    __syncthreads();
    if (lane<8){
      float s=0.f;
#pragma unroll
      for (int a=0;a<16;a++) s += S[1024+lane*16+a];
      float ea = __expf(s);
      expa[(size_t)e*8+lane] = ea;
      unsafeAtomicAdd(&asum[(size_t)dst*8+lane], ea);
    }
    __syncthreads();
  }
}

// ---------------- K3: MFMA edge kernel (unchanged from round 2) ----------------
__global__ __launch_bounds__(256,4) void k_edge(
  const __hip_bfloat16* __restrict__ h, const int* __restrict__ ei,
  const float* __restrict__ wig,
  const short* __restrict__ w1t, const short* __restrict__ togA,
  const short* __restrict__ fgA,
  const float* __restrict__ expa, const float* __restrict__ asum,
  const __hip_bfloat16* __restrict__ rfS, const __hip_bfloat16* __restrict__ gateS,
  float* __restrict__ agg)
{
  __shared__ __align__(16) short POOL[16032];
  float* rfull = (float*)&POOL[14592];
  float* gateL = (float*)&POOL[15872];
  float* ahead = (float*)&POOL[16000];
  const int tid = threadIdx.x;
  const int wv = tid>>6, lane = tid&63, lo = lane&15, q = lane>>4;
  const int e = blockIdx.x;
  const int src = ei[e], dst = ei[NE+e];

  {
    int4 z; z.x=0; z.y=0; z.z=0; z.w=0;
    int4* zp = (int4*)POOL;
    for (int idx=tid; idx<960; idx+=256) zp[idx] = z;
  }
  __syncthreads();
  for (int idx=tid; idx<625; idx+=256){
    int i = idx/25, j = idx-25*i;
    short v = f2b(wig[(size_t)e*625+idx]);
    POOL[5120 + i*40 + j] = v;
    POOL[6400 + j*40 + i] = v;
  }
  {
    const __hip_bfloat16* hs = h + (size_t)src*1600;
    const __hip_bfloat16* hd = h + (size_t)dst*1600;
    for (int idx=tid; idx<400; idx+=256){
      int nh = idx/200, rem = idx-200*nh;
      int j = rem>>3, cg = rem&7;
      const __hip_bfloat16* hp = nh ? hd : hs;
      uint4 v = *(const uint4*)(hp + j*64 + cg*8);
      unsigned el[8] = {v.x&0xffffu, v.x>>16, v.y&0xffffu, v.y>>16,
                        v.z&0xffffu, v.z>>16, v.w&0xffffu, v.w>>16};
      int cb = nh*64 + cg*8;
#pragma unroll
      for (int qq=0;qq<8;qq++) POOL[(cb+qq)*40 + j] = (short)el[qq];
    }
  }
  for (int idx=tid; idx<640; idx+=256) rfull[idx] = __bfloat162float(rfS[(size_t)e*640+idx]);
  if (tid<64) gateL[tid] = silu_f(__bfloat162float(gateS[(size_t)e*64+tid]));
  else if (tid<72) ahead[tid-64] = expa[(size_t)e*8+(tid-64)] / (asum[(size_t)dst*8+(tid-64)] + 1e-8f);
  __syncthreads();

  { // rot1
    f32x4 zf = {0.f,0.f,0.f,0.f};
    f32x4 acc[2][2] = {{zf,zf},{zf,zf}};
    bfrag8 b0 = *(const bfrag8*)&POOL[5120 + (lo)*40 + q*8];
    bfrag8 b1 = *(const bfrag8*)&POOL[5120 + (16+lo)*40 + q*8];
#pragma unroll
    for (int t=0;t<2;t++){
      int mrow = (2*wv+t)*16 + lo;
      bfrag8 a = *(const bfrag8*)&POOL[mrow*40 + q*8];
      acc[t][0] = __builtin_amdgcn_mfma_f32_16x16x32_bf16(a, b0, acc[t][0], 0,0,0);
      acc[t][1] = __builtin_amdgcn_mfma_f32_16x16x32_bf16(a, b1, acc[t][1], 0,0,0);
    }
#pragma unroll
    for (int t=0;t<2;t++){
      int c0 = (2*wv+t)*16 + q*4;
#pragma unroll
      for (int nt=0;nt<2;nt++){
        int i = nt*16 + lo;
        int l = (i>=16)?4:((i>=9)?3:((i>=4)?2:((i>=1)?1:0)));
        const f32x4 rv = *(const f32x4*)&rfull[l*128 + c0];
        s16x4 o;
#pragma unroll
        for (int r=0;r<4;r++) o[r] = f2b(acc[t][nt][r]*rv[r]);
        *(s16x4*)&POOL[7680 + i*136 + c0] = o;
      }
    }
  }
  __syncthreads();

  { // msg
    const int hh = wv*16 + lo;
    f32x4 zf = {0.f,0.f,0.f,0.f};
    f32x4 acc[2] = {zf,zf};
#pragma unroll
    for (int kt=0;kt<4;kt++){
      bfrag8 b = *(const bfrag8*)&w1t[hh*136 + kt*32 + q*8];
#pragma unroll
      for (int t=0;t<2;t++){
        bfrag8 a = *(const bfrag8*)&POOL[7680 + (t*16+lo)*136 + kt*32 + q*8];
        acc[t] = __builtin_amdgcn_mfma_f32_16x16x32_bf16(a, b, acc[t], 0,0,0);
      }
    }
#pragma unroll
    for (int t=0;t<2;t++){
      s16x4 o;
#pragma unroll
      for (int r=0;r<4;r++) o[r] = f2b(acc[t][r]);
      *(s16x4*)&POOL[12032 + hh*40 + t*16 + q*4] = o;
    }
  }
  __syncthreads();

  { // grid fwd
    const int hh = wv*16 + lo;
    bfrag8 b = *(const bfrag8*)&POOL[12032 + hh*40 + q*8];
    f32x4 zf = {0.f,0.f,0.f,0.f};
    f32x4 acc[3] = {zf,zf,zf};
#pragma unroll
    for (int t=0;t<3;t++){
      bfrag8 a = *(const bfrag8*)&togA[(t*16+lo)*40 + q*8];
      acc[t] = __builtin_amdgcn_mfma_f32_16x16x32_bf16(a, b, acc[t], 0,0,0);
    }
#pragma unroll
    for (int t=0;t<3;t++){
      s16x4 o;
#pragma unroll
      for (int r=0;r<4;r++) o[r] = f2b(silu_f(acc[t][r]));
      *(s16x4*)&POOL[hh*72 + t*16 + q*4] = o;
    }
  }
  __syncthreads();

  { // grid bwd
    const int hh = wv*16 + lo;
    f32x4 zf = {0.f,0.f,0.f,0.f};
    f32x4 acc[2] = {zf,zf};
#pragma unroll
    for (int kt=0;kt<2;kt++){
      bfrag8 b = *(const bfrag8*)&POOL[hh*72 + kt*32 + q*8];
#pragma unroll
      for (int t=0;t<2;t++){
        bfrag8 a = *(const bfrag8*)&fgA[(t*16+lo)*72 + kt*32 + q*8];
        acc[t] = __builtin_amdgcn_mfma_f32_16x16x32_bf16(a, b, acc[t], 0,0,0);
      }
    }
    float ah = ahead[hh>>3];
#pragma unroll
    for (int t=0;t<2;t++){
      s16x4 o;
#pragma unroll
      for (int r=0;r<4;r++){
        int j = t*16 + q*4 + r;
        float v = acc[t][r];
        if (j==0) v = gateL[hh];
        o[r] = f2b(v*ah);
      }
      *(s16x4*)&POOL[7680 + hh*40 + t*16 + q*4] = o;
    }
  }
  __syncthreads();

  { // rot2 + scatter
    const int hh = wv*16 + lo;
    bfrag8 b = *(const bfrag8*)&POOL[7680 + hh*40 + q*8];
    f32x4 zf = {0.f,0.f,0.f,0.f};
    f32x4 acc[2] = {zf,zf};
#pragma unroll
    for (int t=0;t<2;t++){
      bfrag8 a = *(const bfrag8*)&POOL[6400 + (t*16+lo)*40 + q*8];
      acc[t] = __builtin_amdgcn_mfma_f32_16x16x32_bf16(a, b, acc[t], 0,0,0);
    }
    float* aggp = agg + (size_t)dst*1600;
#pragma unroll
    for (int t=0;t<2;t++){
#pragma unroll
      for (int r=0;r<4;r++){
        int i = t*16 + q*4 + r;
        if (i<25) unsafeAtomicAdd(&aggp[i*64+hh], acc[t][r]);
      }
    }
  }
}

// ---------------- K4: node update + FFN, MFMA version ----------------
// LDS (shorts): xF(f32)@0 [32][68]=4352sh ; sgB@4352 [128][72]=9216sh
//   (hh2B [32][72] aliases sgB) ; f1B@13568 [128][40]=5120sh
//   (aggB [32][72] and xgB [32][136] alias f1B) ;
//   invc(f32)@18688sh [64] ; gateF(f32)@18816sh [128]  -> 19072 sh = 38144 B
__global__ __launch_bounds__(256,4) void k_node(
  const float* __restrict__ x, const float* __restrict__ aggin,
  const short* __restrict__ projT, const float* __restrict__ gamma2,
  const float* __restrict__ glw, const float* __restrict__ glb,
  const short* __restrict__ fw1T, const float* __restrict__ fb1,
  const short* __restrict__ fw2T, const float* __restrict__ fb2,
  const short* __restrict__ togA, const short* __restrict__ fgA,
  float* __restrict__ out)
{
  __shared__ __align__(16) short P[19072];
  float* xF    = (float*)P;
  short* sgB   = P + 4352;
  short* hh2B  = P + 4352;
  short* f1B   = P + 13568;
  short* aggB  = P + 13568;
  short* xgB   = P + 13568;
  float* invc  = ((float*)P) + 9344;
  float* gateF = ((float*)P) + 9408;
  const int tid = threadIdx.x;
  const int wv = tid>>6, lane = tid&63, lo = lane&15, q = lane>>4;
  const int n = blockIdx.x;
  const s16x4 z4 = {0,0,0,0};

  // stage0: stage aggB; zero NaN-hazard regions
  for (int idx=tid; idx<400; idx+=256){
    int i = idx>>4, k = (idx&15)*4;
    const float4 v = *(const float4*)(aggin + (size_t)n*1600 + (size_t)idx*4);
    s16x4 o; o[0]=f2b(v.x); o[1]=f2b(v.y); o[2]=f2b(v.z); o[3]=f2b(v.w);
    *(s16x4*)&aggB[i*72 + k] = o;
  }
  for (int idx=tid; idx<126; idx+=256)       // hh2B rows 25..31 -> 0
    *(s16x4*)&hh2B[25*72 + idx*4] = z4;
  for (int idx=tid; idx<512; idx+=256){      // sgB[:,48:64) -> 0
    int f = idx>>2, gg = 48 + (idx&3)*4;
    *(s16x4*)&sgB[f*72 + gg] = z4;
  }
  __syncthreads();

  { // stage1: xnew = x + agg@proj. M=i(2) N=c(1/wave) K=64(2)
    f32x4 zf={0.f,0.f,0.f,0.f}; f32x4 acc[2]={zf,zf};
    const int c = wv*16 + lo;
#pragma unroll
    for (int kt=0;kt<2;kt++){
      bfrag8 b = *(const bfrag8*)&projT[c*64 + kt*32 + q*8];
#pragma unroll
      for (int t=0;t<2;t++){
        bfrag8 a = *(const bfrag8*)&aggB[(t*16+lo)*72 + kt*32 + q*8];
        acc[t] = __builtin_amdgcn_mfma_f32_16x16x32_bf16(a,b,acc[t],0,0,0);
      }
    }
#pragma unroll
    for (int t=0;t<2;t++)
#pragma unroll
      for (int r=0;r<4;r++){
        int i = t*16 + q*4 + r;
        if (i<25) xF[i*68+c] = acc[t][r] + x[(size_t)n*1600 + i*64 + c];
      }
  }
  __syncthreads();
  if (tid<64){
    float ss=0.f;
#pragma unroll
    for (int i=0;i<25;i++){ float v = xF[i*68+tid]; ss += v*v; }
    invc[tid] = gamma2[tid]*rsqrtf(ss*(1.f/25.f)+1e-6f);
  }
  __syncthreads();
  for (int idx=tid; idx<1600; idx+=256){
    int i=idx>>6, c=idx&63;
    hh2B[i*72+c] = f2b(xF[i*68+c]*invc[c]);
  }
  if (tid<128){
    float a = glb[tid];
#pragma unroll 8
    for (int c=0;c<64;c++) a += xF[c]*invc[c]*glw[c*128+tid];
    gateF[tid] = silu_f(a);
  }
  __syncthreads();

  { // stage4: f1 = hh2 @ fw1. M=i(2) N=f(2/wave) K=64(2) -> f1B[f][i]
    f32x4 zf={0.f,0.f,0.f,0.f}; f32x4 acc[2][2]={{zf,zf},{zf,zf}};
#pragma unroll
    for (int kt=0;kt<2;kt++){
      bfrag8 a0 = *(const bfrag8*)&hh2B[(lo)*72 + kt*32 + q*8];
      bfrag8 a1 = *(const bfrag8*)&hh2B[(16+lo)*72 + kt*32 + q*8];
#pragma unroll
      for (int s=0;s<2;s++){
        int f = wv*32 + s*16 + lo;
        bfrag8 b = *(const bfrag8*)&fw1T[f*64 + kt*32 + q*8];
        acc[0][s] = __builtin_amdgcn_mfma_f32_16x16x32_bf16(a0,b,acc[0][s],0,0,0);
        acc[1][s] = __builtin_amdgcn_mfma_f32_16x16x32_bf16(a1,b,acc[1][s],0,0,0);
      }
    }
#pragma unroll
    for (int s=0;s<2;s++){
      int f = wv*32 + s*16 + lo;
      float bb = fb1[f];
#pragma unroll
      for (int t=0;t<2;t++){
        s16x4 o;
#pragma unroll
        for (int r=0;r<4;r++){
          int i = t*16+q*4+r;
          o[r] = f2b(acc[t][s][r] + (i==0 ? bb : 0.f));
        }
        *(s16x4*)&f1B[f*40 + t*16 + q*4] = o;
      }
    }
  }
  __syncthreads();

  { // stage5: sg = silu(tog @ f1). M=g(3) N=f(2/wave) K=32 -> sgB[f][g]
    f32x4 zf={0.f,0.f,0.f,0.f}; f32x4 acc[3][2]={{zf,zf},{zf,zf},{zf,zf}};
    bfrag8 a0 = *(const bfrag8*)&togA[(lo)*40 + q*8];
    bfrag8 a1 = *(const bfrag8*)&togA[(16+lo)*40 + q*8];
    bfrag8 a2 = *(const bfrag8*)&togA[(32+lo)*40 + q*8];
#pragma unroll
    for (int s=0;s<2;s++){
      int f = wv*32 + s*16 + lo;
      bfrag8 b = *(const bfrag8*)&f1B[f*40 + q*8];
      acc[0][s] = __builtin_amdgcn_mfma_f32_16x16x32_bf16(a0,b,acc[0][s],0,0,0);
      acc[1][s] = __builtin_amdgcn_mfma_f32_16x16x32_bf16(a1,b,acc[1][s],0,0,0);
      acc[2][s] = __builtin_amdgcn_mfma_f32_16x16x32_bf16(a2,b,acc[2][s],0,0,0);
    }
#pragma unroll
    for (int s=0;s<2;s++){
      int f = wv*32 + s*16 + lo;
#pragma unroll
      for (int t=0;t<3;t++){
        s16x4 o;
#pragma unroll
        for (int r=0;r<4;r++) o[r] = f2b(silu_f(acc[t][s][r]));
        *(s16x4*)&sgB[f*72 + t*16 + q*4] = o;
      }
    }
  }
  __syncthreads();

  { // stage6 (transposed grid bwd): D[f][j] = sum_g sgB[f][g]*fgA[j][g]
    // M=f(2/wave) N=j(2) K=64(2) -> xgB[j][f] (+gate row j==0)
    f32x4 zf={0.f,0.f,0.f,0.f}; f32x4 acc[2][2]={{zf,zf},{zf,zf}};
#pragma unroll
    for (int kt=0;kt<2;kt++){
#pragma unroll
      for (int t=0;t<2;t++){
        bfrag8 b = *(const bfrag8*)&fgA[(t*16+lo)*72 + kt*32 + q*8];
#pragma unroll
        for (int s=0;s<2;s++){
          bfrag8 a = *(const bfrag8*)&sgB[(wv*32+s*16+lo)*72 + kt*32 + q*8];
          acc[s][t] = __builtin_amdgcn_mfma_f32_16x16x32_bf16(a,b,acc[s][t],0,0,0);
        }
      }
    }
#pragma unroll
    for (int s=0;s<2;s++){
      int f0 = wv*32 + s*16 + q*4;
#pragma unroll
      for (int t=0;t<2;t++){
        int j = t*16 + lo;
        s16x4 o;
#pragma unroll
        for (int r=0;r<4;r++)
          o[r] = f2b(j==0 ? gateF[f0+r] : acc[s][t][r]);
        *(s16x4*)&xgB[j*136 + f0] = o;
      }
    }
  }
  __syncthreads();

  { // stage7: f2 = xg @ fw2. M=i(2) N=c(1/wave) K=128(4); out = xnew + f2 (+fb2 row0)
    f32x4 zf={0.f,0.f,0.f,0.f}; f32x4 acc[2]={zf,zf};
    const int c = wv*16 + lo;
#pragma unroll
    for (int kt=0;kt<4;kt++){
      bfrag8 b = *(const bfrag8*)&fw2T[c*128 + kt*32 + q*8];
#pragma unroll
      for (int t=0;t<2;t++){
        bfrag8 a = *(const bfrag8*)&xgB[(t*16+lo)*136 + kt*32 + q*8];
        acc[t] = __builtin_amdgcn_mfma_f32_16x16x32_bf16(a,b,acc[t],0,0,0);
      }
    }
    float bb = fb2[c];
#pragma unroll
    for (int t=0;t<2;t++)
#pragma unroll
      for (int r=0;r<4;r++){
        int i = t*16 + q*4 + r;
        if (i<25)
          out[(size_t)n*1600 + i*64 + c] = xF[i*68+c] + acc[t][r] + (i==0 ? bb : 0.f);
      }
  }
}

extern "C" void kernel_launch(void* const* d_in, const int* in_sizes, int n_in,
                              void* d_out, int out_size, void* d_ws, size_t ws_size,
                              hipStream_t stream) {
  (void)in_sizes; (void)n_in; (void)ws_size;
  const float* x     = (const float*)d_in[0];
  const int*   ei    = (const int*)d_in[1];
  const int*   an    = (const int*)d_in[2];
  const float* edist = (const float*)d_in[3];
  const float* wig   = (const float*)d_in[4];
  const float* stab  = (const float*)d_in[5];
  const float* ttab  = (const float*)d_in[6];
  const float* rw1   = (const float*)d_in[7];
  const float* rb1   = (const float*)d_in[8];
  const float* rw2   = (const float*)d_in[9];
  const float* rb2   = (const float*)d_in[10];
  const float* rw3   = (const float*)d_in[11];
  const float* rb3   = (const float*)d_in[12];
  const float* W1    = (const float*)d_in[13];
  const float* w0e   = (const float*)d_in[14];
  const float* adot  = (const float*)d_in[15];
  const float* tog   = (const float*)d_in[16];
  const float* fromg = (const float*)d_in[17];
  const float* proj  = (const float*)d_in[18];
  const float* g1    = (const float*)d_in[19];
  const float* g2    = (const float*)d_in[20];
  const float* glw   = (const float*)d_in[21];
  const float* glb   = (const float*)d_in[22];
  const float* fw1   = (const float*)d_in[23];
  const float* fb1   = (const float*)d_in[24];
  const float* fw2   = (const float*)d_in[25];
  const float* fb2   = (const float*)d_in[26];
  float* out = (float*)d_out;

  char* wsb = (char*)d_ws;
  __hip_bfloat16* hbuf  = (__hip_bfloat16*)(wsb);               // N*1600 bf16
  __hip_bfloat16* rfS   = (__hip_bfloat16*)(wsb + 32000000);    // E*640 bf16
  __hip_bfloat16* gateS = (__hip_bfloat16*)(wsb + 96000000);    // E*64 bf16
  float*          expa  = (float*)(wsb + 102400000);            // E*8 f32
  float*          asum  = (float*)(wsb + 104000000);            // N*8 f32
  short*          w1t   = (short*)(wsb + 104320000);            // 64*136
  short*          togA  = (short*)(wsb + 104337408);            // 48*40
  short*          fgA   = (short*)(wsb + 104341248);            // 32*72
  short*          projT = (short*)(wsb + 104345856);            // 64*64
  short*          fw1T  = (short*)(wsb + 104354048);            // 128*64
  short*          fw2T  = (short*)(wsb + 104370432);            // 64*128

  hipMemsetAsync(asum, 0, (size_t)NN*8*sizeof(float), stream);
  hipMemsetAsync(d_out, 0, (size_t)out_size*sizeof(float), stream);  // d_out = agg

  k_wprep<<<32, 256, 0, stream>>>(W1, tog, fromg, proj, fw1, fw2,
                                  w1t, togA, fgA, projT, fw1T, fw2T);
  k_rms1 <<<(NN*64+255)/256, 256, 0, stream>>>(x, g1, hbuf);
  k_alpha<<<NE/16, 256, 0, stream>>>(hbuf, ei, an, edist, wig, stab, ttab,
                                     rw1, rb1, rw2, rb2, rw3, rb3, w0e, adot,
                                     expa, asum, rfS, gateS);
  k_edge <<<NE, 256, 0, stream>>>(hbuf, ei, wig, w1t, togA, fgA,
                                  expa, asum, rfS, gateS, out);
  k_node <<<NN, 256, 0, stream>>>(x, out, projT, g2, glw, glb,
                                  fw1T, fb1, fw2T, fb2, togA, fgA, out);
}

// Round 4
// 1115.296 us; speedup vs baseline: 3.1237x; 1.2091x over previous
//
#include <hip/hip_runtime.h>
#include <hip/hip_bf16.h>

#define NN 10000
#define NE 50000

typedef __attribute__((ext_vector_type(8))) short bfrag8;  // 8 bf16 = 4 VGPR (MFMA A/B)
typedef __attribute__((ext_vector_type(4))) short s16x4;   // 4 bf16 = b64 store
typedef __attribute__((ext_vector_type(4))) float f32x4;   // MFMA C/D

__device__ __forceinline__ float silu_f(float v){ return v / (1.0f + __expf(-v)); }
__device__ __forceinline__ short f2b(float f){           // f32 -> bf16 RNE
  unsigned u = __float_as_uint(f);
  u += 0x7fffu + ((u>>16)&1u);
  return (short)(u>>16);
}
__device__ __forceinline__ float b2f(short s){
  return __uint_as_float(((unsigned)(unsigned short)s)<<16);
}

// ---------------- K0: h = rmsnorm(x, gamma1) -> bf16 ----------------
__global__ __launch_bounds__(256) void k_rms1(const float* __restrict__ x,
                                              const float* __restrict__ gamma,
                                              __hip_bfloat16* __restrict__ h){
  int idx = blockIdx.x*256 + threadIdx.x;
  if (idx >= NN*64) return;
  int n = idx>>6, c = idx&63;
  const float* xp = x + (size_t)n*1600 + c;
  float ss = 0.f;
#pragma unroll
  for (int i=0;i<25;i++){ float v = xp[i*64]; ss += v*v; }
  float inv = gamma[c] * rsqrtf(ss*(1.f/25.f) + 1e-6f);
  __hip_bfloat16* hp = h + (size_t)n*1600 + c;
#pragma unroll
  for (int i=0;i<25;i++) hp[i*64] = __float2bfloat16(xp[i*64]*inv);
}

// ------------- Kprep: weights -> MFMA bf16 layouts -------------
__global__ void k_wprep(const float* __restrict__ W1, const float* __restrict__ tog,
                        const float* __restrict__ fromg, const float* __restrict__ proj,
                        const float* __restrict__ fw1, const float* __restrict__ fw2,
                        const float* __restrict__ rw1, const float* __restrict__ rw2,
                        const float* __restrict__ rw3, const float* __restrict__ w0e,
                        short* __restrict__ w1t, short* __restrict__ togA,
                        short* __restrict__ fgA, short* __restrict__ projT,
                        short* __restrict__ fw1T, short* __restrict__ fw2T,
                        short* __restrict__ rw1T, short* __restrict__ rw2T,
                        short* __restrict__ rw3T, short* __restrict__ w0eP){
  int t0 = blockIdx.x*blockDim.x + threadIdx.x;
  int stride = gridDim.x*blockDim.x;
  for (int idx=t0; idx<64*136; idx+=stride){
    int hh = idx/136, k = idx-136*hh;
    w1t[idx] = (k<128) ? f2b(W1[k*64+hh]) : (short)0;
  }
  for (int idx=t0; idx<48*40; idx+=stride){
    int g = idx/40, i = idx-40*g;
    togA[idx] = (g<36 && i<25) ? f2b(tog[g*25+i]) : (short)0;
  }
  for (int idx=t0; idx<32*72; idx+=stride){
    int j = idx/72, g = idx-72*j;
    fgA[idx] = (j<25 && g<36) ? f2b(fromg[j*36+g]) : (short)0;
  }
  for (int idx=t0; idx<64*64; idx+=stride){   // projT[c][k] = proj[k][c]
    int c = idx>>6, k = idx&63;
    projT[idx] = f2b(proj[k*64+c]);
  }
  for (int idx=t0; idx<128*64; idx+=stride){  // fw1T[f][c] = fw1[c][f]
    int f = idx>>6, c = idx&63;
    fw1T[idx] = f2b(fw1[c*128+f]);
  }
  for (int idx=t0; idx<64*128; idx+=stride){  // fw2T[c][f] = fw2[f][c]
    int c = idx>>7, f = idx&127;
    fw2T[idx] = f2b(fw2[f*64+c]);
  }
  for (int idx=t0; idx<64*96; idx+=stride){   // rw1T[n][k] = rw1[k][n]
    int n = idx/96, k = idx-96*n;
    rw1T[idx] = f2b(rw1[k*64+n]);
  }
  for (int idx=t0; idx<64*64; idx+=stride){   // rw2T[n][k] = rw2[k][n]
    int n = idx>>6, k = idx&63;
    rw2T[idx] = f2b(rw2[k*64+n]);
  }
  for (int idx=t0; idx<640*64; idx+=stride){  // rw3T[n][k] = rw3[k][n]
    int n = idx>>6, k = idx&63;
    rw3T[idx] = f2b(rw3[(size_t)k*640+n]);
  }
  for (int idx=t0; idx<128*192; idx+=stride)  // w0eP = w0e (bf16 copy)
    w0eP[idx] = f2b(w0e[idx]);
}

// ---------------- K1: radial MLP, MFMA, 32 edges/block ----------------
// LDS (shorts): efB@0 [32][104]=3328 ; r1B@3328 [32][72]=2304 ;
//               r2B@5632 [32][72]=2304 -> 7936 sh = 15872 B
__global__ __launch_bounds__(256,4) void k_radial(
  const int* __restrict__ ei, const int* __restrict__ an,
  const float* __restrict__ edist,
  const float* __restrict__ stab, const float* __restrict__ ttab,
  const short* __restrict__ rw1T, const float* __restrict__ rb1,
  const short* __restrict__ rw2T, const float* __restrict__ rb2,
  const short* __restrict__ rw3T, const float* __restrict__ rb3,
  short* __restrict__ rfS)
{
  __shared__ __align__(16) short SP[7936];
  const int tid = threadIdx.x;
  const int wv = tid>>6, lane = tid&63, lo = lane&15, q = lane>>4;
  const int e0 = blockIdx.x*32;
  { // stage ef[e][k]: 0..31 edist, 32..63 src_tab, 64..95 tgt_tab
    int e = tid>>3;
    int ee = min(e0+e, NE-1);
    int srcE = ei[ee], dstE = ei[NE+ee];
    const float* dp = edist + (size_t)ee*32;
    const float* sp = stab + (size_t)an[srcE]*32;
    const float* tp = ttab + (size_t)an[dstE]*32;
    int kb = tid&7;
#pragma unroll
    for (int it=0; it<12; ++it){
      int k = kb + it*8;
      float v = (k<32) ? dp[k] : (k<64 ? sp[k-32] : tp[k-64]);
      SP[e*104+k] = f2b(v);
    }
  }
  __syncthreads();
  { // r1 = silu(ef @ rw1 + b1): M=n1(wave's 16), N=e(32), K=96
    f32x4 zf={0.f,0.f,0.f,0.f}; f32x4 acc[2]={zf,zf};
#pragma unroll
    for (int kt=0;kt<3;kt++){
      bfrag8 a = *(const bfrag8*)&rw1T[(wv*16+lo)*96 + kt*32 + q*8];
#pragma unroll
      for (int et=0;et<2;et++){
        bfrag8 b = *(const bfrag8*)&SP[(et*16+lo)*104 + kt*32 + q*8];
        acc[et] = __builtin_amdgcn_mfma_f32_16x16x32_bf16(a,b,acc[et],0,0,0);
      }
    }
    int n1 = wv*16 + q*4;
    const float4 bb = *(const float4*)&rb1[n1];
#pragma unroll
    for (int et=0;et<2;et++){
      s16x4 o;
      o[0]=f2b(silu_f(acc[et][0]+bb.x)); o[1]=f2b(silu_f(acc[et][1]+bb.y));
      o[2]=f2b(silu_f(acc[et][2]+bb.z)); o[3]=f2b(silu_f(acc[et][3]+bb.w));
      *(s16x4*)&SP[3328 + (et*16+lo)*72 + n1] = o;
    }
  }
  __syncthreads();
  { // r2 = silu(r1 @ rw2 + b2): K=64
    f32x4 zf={0.f,0.f,0.f,0.f}; f32x4 acc[2]={zf,zf};
#pragma unroll
    for (int kt=0;kt<2;kt++){
      bfrag8 a = *(const bfrag8*)&rw2T[(wv*16+lo)*64 + kt*32 + q*8];
#pragma unroll
      for (int et=0;et<2;et++){
        bfrag8 b = *(const bfrag8*)&SP[3328 + (et*16+lo)*72 + kt*32 + q*8];
        acc[et] = __builtin_amdgcn_mfma_f32_16x16x32_bf16(a,b,acc[et],0,0,0);
      }
    }
    int n2 = wv*16 + q*4;
    const float4 bb = *(const float4*)&rb2[n2];
#pragma unroll
    for (int et=0;et<2;et++){
      s16x4 o;
      o[0]=f2b(silu_f(acc[et][0]+bb.x)); o[1]=f2b(silu_f(acc[et][1]+bb.y));
      o[2]=f2b(silu_f(acc[et][2]+bb.z)); o[3]=f2b(silu_f(acc[et][3]+bb.w));
      *(s16x4*)&SP[5632 + (et*16+lo)*72 + n2] = o;
    }
  }
  __syncthreads();
  { // r3 = r2 @ rw3 + b3 -> rfS bf16 global. M=640 (10 m-tiles/wave), K=64
    bfrag8 bfr[2][2];
#pragma unroll
    for (int et=0;et<2;et++)
#pragma unroll
      for (int kt=0;kt<2;kt++)
        bfr[et][kt] = *(const bfrag8*)&SP[5632 + (et*16+lo)*72 + kt*32 + q*8];
    for (int mi=0; mi<10; ++mi){
      int n3base = (wv + mi*4)*16;
      f32x4 zf={0.f,0.f,0.f,0.f}; f32x4 acc[2]={zf,zf};
#pragma unroll
      for (int kt=0;kt<2;kt++){
        bfrag8 a = *(const bfrag8*)&rw3T[(size_t)(n3base+lo)*64 + kt*32 + q*8];
        acc[0] = __builtin_amdgcn_mfma_f32_16x16x32_bf16(a,bfr[0][kt],acc[0],0,0,0);
        acc[1] = __builtin_amdgcn_mfma_f32_16x16x32_bf16(a,bfr[1][kt],acc[1],0,0,0);
      }
      int n3 = n3base + q*4;
      const float4 bb = *(const float4*)&rb3[n3];
#pragma unroll
      for (int et=0;et<2;et++){
        int e = e0 + et*16 + lo;
        if (e < NE){
          s16x4 o;
          o[0]=f2b(acc[et][0]+bb.x); o[1]=f2b(acc[et][1]+bb.y);
          o[2]=f2b(acc[et][2]+bb.z); o[3]=f2b(acc[et][3]+bb.w);
          *(s16x4*)&rfS[(size_t)e*640 + n3] = o;
        }
      }
    }
  }
}

// ---------------- K3: MFMA edge kernel + fused alpha/gate ----------------
// POOL (shorts): hcatT@0[128][40] (aliased by sgB[64][72])  wA@5120[32][40]
//   wT@6400[32][40]  xeB@7680[32][136] (aliased by msgs2B[64][40])
//   msgsB@12032[64][40]  rfull(f32)@14592[640]  gateL(f32)@15872[64]
//   ahead(f32)@16000[8]  exL(f32)@16032[128] -> 16288 sh = 32576 B
__global__ __launch_bounds__(256,4) void k_edge(
  const __hip_bfloat16* __restrict__ h, const int* __restrict__ ei,
  const float* __restrict__ wig,
  const short* __restrict__ w1t, const short* __restrict__ togA,
  const short* __restrict__ fgA, const short* __restrict__ w0eP,
  const float* __restrict__ adot,
  const short* __restrict__ rfS, float* __restrict__ asum,
  float* __restrict__ agg)
{
  __shared__ __align__(16) short POOL[16288];
  float* rfull = (float*)&POOL[14592];
  float* gateL = (float*)&POOL[15872];
  float* ahead = (float*)&POOL[16000];
  float* exL   = (float*)&POOL[16032];
  const int tid = threadIdx.x;
  const int wv = tid>>6, lane = tid&63, lo = lane&15, q = lane>>4;
  const int e = blockIdx.x;
  const int src = ei[e], dst = ei[NE+e];

  { // zero hcatT+wA+wT (K-padding correctness)
    int4 z; z.x=0; z.y=0; z.z=0; z.w=0;
    int4* zp = (int4*)POOL;
    for (int idx=tid; idx<960; idx+=256) zp[idx] = z;
  }
  __syncthreads();
  for (int idx=tid; idx<625; idx+=256){
    int i = idx/25, j = idx-25*i;
    short v = f2b(wig[(size_t)e*625+idx]);
    POOL[5120 + i*40 + j] = v;
    POOL[6400 + j*40 + i] = v;
  }
  {
    const __hip_bfloat16* hs = h + (size_t)src*1600;
    const __hip_bfloat16* hd = h + (size_t)dst*1600;
    for (int idx=tid; idx<400; idx+=256){
      int nh = idx/200, rem = idx-200*nh;
      int j = rem>>3, cg = rem&7;
      const __hip_bfloat16* hp = nh ? hd : hs;
      uint4 v = *(const uint4*)(hp + j*64 + cg*8);
      unsigned el[8] = {v.x&0xffffu, v.x>>16, v.y&0xffffu, v.y>>16,
                        v.z&0xffffu, v.z>>16, v.w&0xffffu, v.w>>16};
      int cb = nh*64 + cg*8;
#pragma unroll
      for (int qq=0;qq<8;qq++) POOL[(cb+qq)*40 + j] = (short)el[qq];
    }
  }
  for (int idx=tid; idx<640; idx+=256) rfull[idx] = b2f(rfS[(size_t)e*640+idx]);
  __syncthreads();

  { // rot1: xe[i][c] = sum_j W[i][j] hcat[j][c], *r (row0 -> xe0r)
    f32x4 zf = {0.f,0.f,0.f,0.f};
    f32x4 acc[2][2] = {{zf,zf},{zf,zf}};
    bfrag8 b0 = *(const bfrag8*)&POOL[5120 + (lo)*40 + q*8];
    bfrag8 b1 = *(const bfrag8*)&POOL[5120 + (16+lo)*40 + q*8];
#pragma unroll
    for (int t=0;t<2;t++){
      int mrow = (2*wv+t)*16 + lo;
      bfrag8 a = *(const bfrag8*)&POOL[mrow*40 + q*8];
      acc[t][0] = __builtin_amdgcn_mfma_f32_16x16x32_bf16(a, b0, acc[t][0], 0,0,0);
      acc[t][1] = __builtin_amdgcn_mfma_f32_16x16x32_bf16(a, b1, acc[t][1], 0,0,0);
    }
#pragma unroll
    for (int t=0;t<2;t++){
      int c0 = (2*wv+t)*16 + q*4;
#pragma unroll
      for (int nt=0;nt<2;nt++){
        int i = nt*16 + lo;
        int l = (i>=16)?4:((i>=9)?3:((i>=4)?2:((i>=1)?1:0)));
        const f32x4 rv = *(const f32x4*)&rfull[l*128 + c0];
        s16x4 o;
#pragma unroll
        for (int r=0;r<4;r++) o[r] = f2b(acc[t][nt][r]*rv[r]);
        *(s16x4*)&POOL[7680 + i*136 + c0] = o;
      }
    }
  }
  __syncthreads();

  { // extra = xe0r @ W0_extra (scalar, threads 0..95, 2 outputs each)
    if (tid < 96){
      float s0=0.f, s1=0.f;
      for (int c=0; c<128; c+=2){
        unsigned xp = *(const unsigned*)&POOL[7680 + c];   // xe0r[c], [c+1]
        float x0 = b2f((short)(xp&0xffffu)), x1 = b2f((short)(xp>>16));
        unsigned wp0 = *(const unsigned*)&w0eP[c*192 + 2*tid];
        unsigned wp1 = *(const unsigned*)&w0eP[(c+1)*192 + 2*tid];
        s0 += x0*b2f((short)(wp0&0xffffu)) + x1*b2f((short)(wp1&0xffffu));
        s1 += x0*b2f((short)(wp0>>16))     + x1*b2f((short)(wp1>>16));
      }
      if (tid < 64){
        int n0 = 2*tid;
        exL[n0]   = silu_f(s0)*adot[n0];
        exL[n0+1] = silu_f(s1)*adot[n0+1];
      } else {
        int g0 = 2*tid - 128;
        gateL[g0]   = silu_f(s0);
        gateL[g0+1] = silu_f(s1);
      }
    }
  }
  { // msg: msgs[i][h] = sum_c xe[i][c] W1[c][h]
    const int hh = wv*16 + lo;
    f32x4 zf = {0.f,0.f,0.f,0.f};
    f32x4 acc[2] = {zf,zf};
#pragma unroll
    for (int kt=0;kt<4;kt++){
      bfrag8 b = *(const bfrag8*)&w1t[hh*136 + kt*32 + q*8];
#pragma unroll
      for (int t=0;t<2;t++){
        bfrag8 a = *(const bfrag8*)&POOL[7680 + (t*16+lo)*136 + kt*32 + q*8];
        acc[t] = __builtin_amdgcn_mfma_f32_16x16x32_bf16(a, b, acc[t], 0,0,0);
      }
    }
#pragma unroll
    for (int t=0;t<2;t++){
      s16x4 o;
#pragma unroll
      for (int r=0;r<4;r++) o[r] = f2b(acc[t][r]);
      *(s16x4*)&POOL[12032 + hh*40 + t*16 + q*4] = o;
    }
  }
  __syncthreads();

  if (tid < 8){ // alpha head-reduce + exp; UNNORMALIZED (k_node divides)
    float s = 0.f;
#pragma unroll
    for (int a=0;a<16;a++) s += exL[tid*16+a];
    float eh = __expf(s);
    ahead[tid] = eh;
    unsafeAtomicAdd(&asum[(size_t)dst*8 + tid], eh);
  }
  { // grid fwd
    const int hh = wv*16 + lo;
    bfrag8 b = *(const bfrag8*)&POOL[12032 + hh*40 + q*8];
    f32x4 zf = {0.f,0.f,0.f,0.f};
    f32x4 acc[3] = {zf,zf,zf};
#pragma unroll
    for (int t=0;t<3;t++){
      bfrag8 a = *(const bfrag8*)&togA[(t*16+lo)*40 + q*8];
      acc[t] = __builtin_amdgcn_mfma_f32_16x16x32_bf16(a, b, acc[t], 0,0,0);
    }
#pragma unroll
    for (int t=0;t<3;t++){
      s16x4 o;
#pragma unroll
      for (int r=0;r<4;r++) o[r] = f2b(silu_f(acc[t][r]));
      *(s16x4*)&POOL[hh*72 + t*16 + q*4] = o;
    }
  }
  __syncthreads();

  { // grid bwd; row0<-gate; * exp(alpha) per head
    const int hh = wv*16 + lo;
    f32x4 zf = {0.f,0.f,0.f,0.f};
    f32x4 acc[2] = {zf,zf};
#pragma unroll
    for (int kt=0;kt<2;kt++){
      bfrag8 b = *(const bfrag8*)&POOL[hh*72 + kt*32 + q*8];
#pragma unroll
      for (int t=0;t<2;t++){
        bfrag8 a = *(const bfrag8*)&fgA[(t*16+lo)*72 + kt*32 + q*8];
        acc[t] = __builtin_amdgcn_mfma_f32_16x16x32_bf16(a, b, acc[t], 0,0,0);
      }
    }
    float ah = ahead[hh>>3];
#pragma unroll
    for (int t=0;t<2;t++){
      s16x4 o;
#pragma unroll
      for (int r=0;r<4;r++){
        int j = t*16 + q*4 + r;
        float v = acc[t][r];
        if (j==0) v = gateL[hh];
        o[r] = f2b(v*ah);
      }
      *(s16x4*)&POOL[7680 + hh*40 + t*16 + q*4] = o;
    }
  }
  __syncthreads();

  { // rot2 + scatter
    const int hh = wv*16 + lo;
    bfrag8 b = *(const bfrag8*)&POOL[7680 + hh*40 + q*8];
    f32x4 zf = {0.f,0.f,0.f,0.f};
    f32x4 acc[2] = {zf,zf};
#pragma unroll
    for (int t=0;t<2;t++){
      bfrag8 a = *(const bfrag8*)&POOL[6400 + (t*16+lo)*40 + q*8];
      acc[t] = __builtin_amdgcn_mfma_f32_16x16x32_bf16(a, b, acc[t], 0,0,0);
    }
    float* aggp = agg + (size_t)dst*1600;
#pragma unroll
    for (int t=0;t<2;t++){
#pragma unroll
      for (int r=0;r<4;r++){
        int i = t*16 + q*4 + r;
        if (i<25) unsafeAtomicAdd(&aggp[i*64+hh], acc[t][r]);
      }
    }
  }
}

// ---------------- K4: node update + FFN, MFMA ----------------
__global__ __launch_bounds__(256,4) void k_node(
  const float* __restrict__ x, const float* __restrict__ aggin,
  const float* __restrict__ asum,
  const short* __restrict__ projT, const float* __restrict__ gamma2,
  const float* __restrict__ glw, const float* __restrict__ glb,
  const short* __restrict__ fw1T, const float* __restrict__ fb1,
  const short* __restrict__ fw2T, const float* __restrict__ fb2,
  const short* __restrict__ togA, const short* __restrict__ fgA,
  float* __restrict__ out)
{
  __shared__ __align__(16) short P[19072];
  float* xF    = (float*)P;
  short* sgB   = P + 4352;
  short* hh2B  = P + 4352;
  short* f1B   = P + 13568;
  short* aggB  = P + 13568;
  short* xgB   = P + 13568;
  float* invc  = ((float*)P) + 9344;
  float* gateF = ((float*)P) + 9408;
  const int tid = threadIdx.x;
  const int wv = tid>>6, lane = tid&63, lo = lane&15, q = lane>>4;
  const int n = blockIdx.x;
  const s16x4 z4 = {0,0,0,0};

  // stage0: stage aggB with per-head softmax denominator; zero hazard regions
  for (int idx=tid; idx<400; idx+=256){
    int i = idx>>4, k = idx&15;
    float sc = 1.f/(asum[(size_t)n*8 + (k>>1)] + 1e-8f);
    const float4 v = *(const float4*)(aggin + (size_t)n*1600 + (size_t)idx*4);
    s16x4 o; o[0]=f2b(v.x*sc); o[1]=f2b(v.y*sc); o[2]=f2b(v.z*sc); o[3]=f2b(v.w*sc);
    *(s16x4*)&aggB[i*72 + k*4] = o;
  }
  for (int idx=tid; idx<126; idx+=256)
    *(s16x4*)&hh2B[25*72 + idx*4] = z4;
  for (int idx=tid; idx<512; idx+=256){
    int f = idx>>2, gg = 48 + (idx&3)*4;
    *(s16x4*)&sgB[f*72 + gg] = z4;
  }
  __syncthreads();

  { // stage1: xnew = x + (agg/denom)@proj
    f32x4 zf={0.f,0.f,0.f,0.f}; f32x4 acc[2]={zf,zf};
    const int c = wv*16 + lo;
#pragma unroll
    for (int kt=0;kt<2;kt++){
      bfrag8 b = *(const bfrag8*)&projT[c*64 + kt*32 + q*8];
#pragma unroll
      for (int t=0;t<2;t++){
        bfrag8 a = *(const bfrag8*)&aggB[(t*16+lo)*72 + kt*32 + q*8];
        acc[t] = __builtin_amdgcn_mfma_f32_16x16x32_bf16(a,b,acc[t],0,0,0);
      }
    }
#pragma unroll
    for (int t=0;t<2;t++)
#pragma unroll
      for (int r=0;r<4;r++){
        int i = t*16 + q*4 + r;
        if (i<25) xF[i*68+c] = acc[t][r] + x[(size_t)n*1600 + i*64 + c];
      }
  }
  __syncthreads();
  if (tid<64){
    float ss=0.f;
#pragma unroll
    for (int i=0;i<25;i++){ float v = xF[i*68+tid]; ss += v*v; }
    invc[tid] = gamma2[tid]*rsqrtf(ss*(1.f/25.f)+1e-6f);
  }
  __syncthreads();
  for (int idx=tid; idx<1600; idx+=256){
    int i=idx>>6, c=idx&63;
    hh2B[i*72+c] = f2b(xF[i*68+c]*invc[c]);
  }
  if (tid<128){
    float a = glb[tid];
#pragma unroll 8
    for (int c=0;c<64;c++) a += xF[c]*invc[c]*glw[c*128+tid];
    gateF[tid] = silu_f(a);
  }
  __syncthreads();

  { // stage4: f1 = hh2 @ fw1 -> f1B[f][i]
    f32x4 zf={0.f,0.f,0.f,0.f}; f32x4 acc[2][2]={{zf,zf},{zf,zf}};
#pragma unroll
    for (int kt=0;kt<2;kt++){
      bfrag8 a0 = *(const bfrag8*)&hh2B[(lo)*72 + kt*32 + q*8];
      bfrag8 a1 = *(const bfrag8*)&hh2B[(16+lo)*72 + kt*32 + q*8];
#pragma unroll
      for (int s=0;s<2;s++){
        int f = wv*32 + s*16 + lo;
        bfrag8 b = *(const bfrag8*)&fw1T[f*64 + kt*32 + q*8];
        acc[0][s] = __builtin_amdgcn_mfma_f32_16x16x32_bf16(a0,b,acc[0][s],0,0,0);
        acc[1][s] = __builtin_amdgcn_mfma_f32_16x16x32_bf16(a1,b,acc[1][s],0,0,0);
      }
    }
#pragma unroll
    for (int s=0;s<2;s++){
      int f = wv*32 + s*16 + lo;
      float bb = fb1[f];
#pragma unroll
      for (int t=0;t<2;t++){
        s16x4 o;
#pragma unroll
        for (int r=0;r<4;r++){
          int i = t*16+q*4+r;
          o[r] = f2b(acc[t][s][r] + (i==0 ? bb : 0.f));
        }
        *(s16x4*)&f1B[f*40 + t*16 + q*4] = o;
      }
    }
  }
  __syncthreads();

  { // stage5: sg = silu(tog @ f1) -> sgB[f][g]
    f32x4 zf={0.f,0.f,0.f,0.f}; f32x4 acc[3][2]={{zf,zf},{zf,zf},{zf,zf}};
    bfrag8 a0 = *(const bfrag8*)&togA[(lo)*40 + q*8];
    bfrag8 a1 = *(const bfrag8*)&togA[(16+lo)*40 + q*8];
    bfrag8 a2 = *(const bfrag8*)&togA[(32+lo)*40 + q*8];
#pragma unroll
    for (int s=0;s<2;s++){
      int f = wv*32 + s*16 + lo;
      bfrag8 b = *(const bfrag8*)&f1B[f*40 + q*8];
      acc[0][s] = __builtin_amdgcn_mfma_f32_16x16x32_bf16(a0,b,acc[0][s],0,0,0);
      acc[1][s] = __builtin_amdgcn_mfma_f32_16x16x32_bf16(a1,b,acc[1][s],0,0,0);
      acc[2][s] = __builtin_amdgcn_mfma_f32_16x16x32_bf16(a2,b,acc[2][s],0,0,0);
    }
#pragma unroll
    for (int s=0;s<2;s++){
      int f = wv*32 + s*16 + lo;
#pragma unroll
      for (int t=0;t<3;t++){
        s16x4 o;
#pragma unroll
        for (int r=0;r<4;r++) o[r] = f2b(silu_f(acc[t][s][r]));
        *(s16x4*)&sgB[f*72 + t*16 + q*4] = o;
      }
    }
  }
  __syncthreads();

  { // stage6: transposed grid bwd -> xgB[j][f] (+gate row j==0)
    f32x4 zf={0.f,0.f,0.f,0.f}; f32x4 acc[2][2]={{zf,zf},{zf,zf}};
#pragma unroll
    for (int kt=0;kt<2;kt++){
#pragma unroll
      for (int t=0;t<2;t++){
        bfrag8 b = *(const bfrag8*)&fgA[(t*16+lo)*72 + kt*32 + q*8];
#pragma unroll
        for (int s=0;s<2;s++){
          bfrag8 a = *(const bfrag8*)&sgB[(wv*32+s*16+lo)*72 + kt*32 + q*8];
          acc[s][t] = __builtin_amdgcn_mfma_f32_16x16x32_bf16(a,b,acc[s][t],0,0,0);
        }
      }
    }
#pragma unroll
    for (int s=0;s<2;s++){
      int f0 = wv*32 + s*16 + q*4;
#pragma unroll
      for (int t=0;t<2;t++){
        int j = t*16 + lo;
        s16x4 o;
#pragma unroll
        for (int r=0;r<4;r++)
          o[r] = f2b(j==0 ? gateF[f0+r] : acc[s][t][r]);
        *(s16x4*)&xgB[j*136 + f0] = o;
      }
    }
  }
  __syncthreads();

  { // stage7: f2 = xg @ fw2; out = xnew + f2 (+fb2 row0)
    f32x4 zf={0.f,0.f,0.f,0.f}; f32x4 acc[2]={zf,zf};
    const int c = wv*16 + lo;
#pragma unroll
    for (int kt=0;kt<4;kt++){
      bfrag8 b = *(const bfrag8*)&fw2T[c*128 + kt*32 + q*8];
#pragma unroll
      for (int t=0;t<2;t++){
        bfrag8 a = *(const bfrag8*)&xgB[(t*16+lo)*136 + kt*32 + q*8];
        acc[t] = __builtin_amdgcn_mfma_f32_16x16x32_bf16(a,b,acc[t],0,0,0);
      }
    }
    float bb = fb2[c];
#pragma unroll
    for (int t=0;t<2;t++)
#pragma unroll
      for (int r=0;r<4;r++){
        int i = t*16 + q*4 + r;
        if (i<25)
          out[(size_t)n*1600 + i*64 + c] = xF[i*68+c] + acc[t][r] + (i==0 ? bb : 0.f);
      }
  }
}

extern "C" void kernel_launch(void* const* d_in, const int* in_sizes, int n_in,
                              void* d_out, int out_size, void* d_ws, size_t ws_size,
                              hipStream_t stream) {
  (void)in_sizes; (void)n_in; (void)ws_size;
  const float* x     = (const float*)d_in[0];
  const int*   ei    = (const int*)d_in[1];
  const int*   an    = (const int*)d_in[2];
  const float* edist = (const float*)d_in[3];
  const float* wig   = (const float*)d_in[4];
  const float* stab  = (const float*)d_in[5];
  const float* ttab  = (const float*)d_in[6];
  const float* rw1   = (const float*)d_in[7];
  const float* rb1   = (const float*)d_in[8];
  const float* rw2   = (const float*)d_in[9];
  const float* rb2   = (const float*)d_in[10];
  const float* rw3   = (const float*)d_in[11];
  const float* rb3   = (const float*)d_in[12];
  const float* W1    = (const float*)d_in[13];
  const float* w0e   = (const float*)d_in[14];
  const float* adot  = (const float*)d_in[15];
  const float* tog   = (const float*)d_in[16];
  const float* fromg = (const float*)d_in[17];
  const float* proj  = (const float*)d_in[18];
  const float* g1    = (const float*)d_in[19];
  const float* g2    = (const float*)d_in[20];
  const float* glw   = (const float*)d_in[21];
  const float* glb   = (const float*)d_in[22];
  const float* fw1   = (const float*)d_in[23];
  const float* fb1   = (const float*)d_in[24];
  const float* fw2   = (const float*)d_in[25];
  const float* fb2   = (const float*)d_in[26];
  float* out = (float*)d_out;

  char* wsb = (char*)d_ws;
  __hip_bfloat16* hbuf = (__hip_bfloat16*)(wsb);         // N*1600 bf16 (32 MB)
  short* rfS   = (short*)(wsb + 32000000);               // E*640 bf16 (64 MB)
  float* asum  = (float*)(wsb + 96000000);               // N*8 f32
  short* w1t   = (short*)(wsb + 96320128);               // 64*136
  short* togA  = (short*)(wsb + 96337600);               // 48*40
  short* fgA   = (short*)(wsb + 96341504);               // 32*72
  short* projT = (short*)(wsb + 96346112);               // 64*64
  short* fw1T  = (short*)(wsb + 96354304);               // 128*64
  short* fw2T  = (short*)(wsb + 96370688);               // 64*128
  short* rw1T  = (short*)(wsb + 96387072);               // 64*96
  short* rw2T  = (short*)(wsb + 96399360);               // 64*64
  short* rw3T  = (short*)(wsb + 96407552);               // 640*64
  short* w0eP  = (short*)(wsb + 96489472);               // 128*192

  hipMemsetAsync(asum, 0, (size_t)NN*8*sizeof(float), stream);
  hipMemsetAsync(d_out, 0, (size_t)out_size*sizeof(float), stream);  // d_out = agg

  k_wprep<<<32, 256, 0, stream>>>(W1, tog, fromg, proj, fw1, fw2, rw1, rw2, rw3, w0e,
                                  w1t, togA, fgA, projT, fw1T, fw2T,
                                  rw1T, rw2T, rw3T, w0eP);
  k_rms1  <<<(NN*64+255)/256, 256, 0, stream>>>(x, g1, hbuf);
  k_radial<<<(NE+31)/32, 256, 0, stream>>>(ei, an, edist, stab, ttab,
                                           rw1T, rb1, rw2T, rb2, rw3T, rb3, rfS);
  k_edge  <<<NE, 256, 0, stream>>>(hbuf, ei, wig, w1t, togA, fgA, w0eP, adot,
                                   rfS, asum, out);
  k_node  <<<NN, 256, 0, stream>>>(x, out, asum, projT, g2, glw, glb,
                                   fw1T, fb1, fw2T, fb2, togA, fgA, out);
}